// Round 1
// baseline (242.655 us; speedup 1.0000x reference)
//
#include <hip/hip_runtime.h>

typedef __attribute__((ext_vector_type(8))) __bf16 bf16x8;
typedef __attribute__((ext_vector_type(4))) __bf16 bf16x4;
typedef __attribute__((ext_vector_type(4))) float  f32x4;
typedef __attribute__((ext_vector_type(4))) float  float4v;

#define DEV static __device__ __forceinline__

DEV void gload_lds16(const void* g, void* l) {
  __builtin_amdgcn_global_load_lds(
      (const __attribute__((address_space(1))) void*)g,
      (__attribute__((address_space(3))) void*)l, 16, 0, 0);
}

// ---------------- f32 -> bf16 convert (vectorized) ----------------
__global__ void cvt_bf16_kernel(const float* __restrict__ in,
                                __bf16* __restrict__ out, int n4) {
  int stride = gridDim.x * blockDim.x;
  for (int i = blockIdx.x * blockDim.x + threadIdx.x; i < n4; i += stride) {
    float4v v = ((const float4v*)in)[i];
    bf16x4 o;
#pragma unroll
    for (int j = 0; j < 4; ++j) o[j] = (__bf16)v[j];
    ((bf16x4*)out)[i] = o;
  }
}

// ---------------- softmax of conv_w (H=4, K=31) ----------------
__global__ void softmax_w_kernel(const float* __restrict__ cw,
                                 float* __restrict__ out) {
  int h = threadIdx.x;
  if (h < 4) {
    float m = cw[h * 31];
#pragma unroll
    for (int k = 1; k < 31; ++k) m = fmaxf(m, cw[h * 31 + k]);
    float e[31];
    float s = 0.f;
#pragma unroll
    for (int k = 0; k < 31; ++k) {
      e[k] = __expf(cw[h * 31 + k] - m);
      s += e[k];
    }
    float inv = 1.f / s;
#pragma unroll
    for (int k = 0; k < 31; ++k) out[h * 31 + k] = e[k] * inv;
  }
}

// ------- GEMM: C[M][N] = A[M][K] * Bw[N][K]^T + bias[N] (m97 structure) -------
// 128x128 tile, BK=32, 256 threads = 4 waves (2x2), 16x16x32 bf16 MFMA.
template <int STORE_BF16>
__global__ __launch_bounds__(256, 2)
void gemm_bt_kernel(const __bf16* __restrict__ A, const __bf16* __restrict__ Bw,
                    const float* __restrict__ bias, void* __restrict__ Cout,
                    int M, int N, int K) {
  __shared__ __align__(16) __bf16 As[128 * 32];
  __shared__ __align__(16) __bf16 Bs[128 * 32];
  const int tid  = threadIdx.x;
  const int lane = tid & 63;
  const int wid  = tid >> 6;
  const int wr = wid >> 1, wc = wid & 1;

  const int m0 = blockIdx.y * 128, n0 = blockIdx.x * 128;

  const f32x4 z = {0.f, 0.f, 0.f, 0.f};
  f32x4 acc[4][4];
#pragma unroll
  for (int i = 0; i < 4; ++i)
#pragma unroll
    for (int j = 0; j < 4; ++j) acc[i][j] = z;

  const int srow = lane >> 2;        // row within a 16-row staging chunk
  const int skq  = (lane & 3) * 8;   // k element offset (8 bf16 = 16B)
  const __bf16* Ab = A + (long)m0 * K;
  const __bf16* Bb = Bw + (long)n0 * K;

  const int frow = lane & 15;        // fragment row/col
  const int fk   = (lane >> 4) * 8;  // fragment k offset

  for (int kt = 0; kt < K; kt += 32) {
    // stage A,B tiles: 8 chunks of 16 rows each, 2 chunks per wave per matrix
#pragma unroll
    for (int j = 0; j < 2; ++j) {
      const int chunk = wid * 2 + j;  // 0..7
      gload_lds16(Ab + (long)(chunk * 16 + srow) * K + kt + skq, As + chunk * 512);
      gload_lds16(Bb + (long)(chunk * 16 + srow) * K + kt + skq, Bs + chunk * 512);
    }
    __syncthreads();
    bf16x8 af[4], bfr[4];
#pragma unroll
    for (int i = 0; i < 4; ++i)
      af[i] = *(const bf16x8*)(As + (wr * 64 + i * 16 + frow) * 32 + fk);
#pragma unroll
    for (int i = 0; i < 4; ++i)
      bfr[i] = *(const bf16x8*)(Bs + (wc * 64 + i * 16 + frow) * 32 + fk);
#pragma unroll
    for (int i = 0; i < 4; ++i)
#pragma unroll
      for (int j = 0; j < 4; ++j)
        acc[i][j] = __builtin_amdgcn_mfma_f32_16x16x32_bf16(af[i], bfr[j],
                                                            acc[i][j], 0, 0, 0);
    __syncthreads();
  }

  // epilogue: C/D layout col=lane&15, row=(lane>>4)*4+reg  [m89/m91-verified]
  const int crow = (lane >> 4) * 4;
  const int ccol = lane & 15;
#pragma unroll
  for (int i = 0; i < 4; ++i) {
#pragma unroll
    for (int j = 0; j < 4; ++j) {
      const int mrow = m0 + wr * 64 + i * 16 + crow;
      const int ncol = n0 + wc * 64 + j * 16 + ccol;
      const float bv = bias[ncol];
#pragma unroll
      for (int r = 0; r < 4; ++r) {
        float v = acc[i][j][r] + bv;
        if (STORE_BF16)
          ((__bf16*)Cout)[(long)(mrow + r) * N + ncol] = (__bf16)v;
        else
          ((float*)Cout)[(long)(mrow + r) * N + ncol] = v;
      }
    }
  }
}

// ------- fused GLU + depthwise conv (K=31, pad 15) + bias + mask -------
// X: (B,T,2C) bf16; Y: (B,T,C) bf16. Block: b x t-tile(64) x c-tile(128).
__global__ __launch_bounds__(256, 2)
void glu_conv_kernel(const __bf16* __restrict__ X, const float* __restrict__ Wsm,
                     const float* __restrict__ bias, const int* __restrict__ mask,
                     __bf16* __restrict__ Y) {
  const int b  = blockIdx.z;
  const int t0 = blockIdx.y * 64;
  const int c0 = blockIdx.x * 128;
  __shared__ float sg[94][128];  // t0-15 .. t0+78
  __shared__ float sw[4][31];
  const int tid = threadIdx.x;
  if (tid < 124) ((float*)sw)[tid] = Wsm[tid];
  for (int i = tid; i < 94 * 128; i += 256) {
    const int tt = i >> 7, cc = i & 127;
    const int t = t0 - 15 + tt;
    float v = 0.f;
    if (t >= 0 && t < 1024) {
      const long base = ((long)b * 1024 + t) * 2048 + c0 + cc;
      const float a = (float)X[base];
      const float g = (float)X[base + 1024];
      v = a / (1.f + __expf(-g));  // a * sigmoid(g)
    }
    sg[tt][cc] = v;
  }
  __syncthreads();
  const int cc = tid & 127;
  const int th = tid >> 7;  // which 32-row half of the t-tile
  const int c  = c0 + cc;
  const float bv = bias[c];
  const float* wrow = sw[c & 3];  // kernel h = c % 4
  for (int tt = 0; tt < 32; ++tt) {
    const int t = th * 32 + tt;
    float s = bv;
#pragma unroll
    for (int k = 0; k < 31; ++k) s += sg[t + k][cc] * wrow[k];
    const int gt = t0 + t;
    if (mask[b * 1024 + gt] == 0) s = 0.f;
    Y[((long)b * 1024 + gt) * 1024 + c] = (__bf16)s;
  }
}

extern "C" void kernel_launch(void* const* d_in, const int* in_sizes, int n_in,
                              void* d_out, int out_size, void* d_ws, size_t ws_size,
                              hipStream_t stream) {
  const float* q    = (const float*)d_in[0];
  const int*   mask = (const int*)d_in[3];
  const float* W1   = (const float*)d_in[4];
  const float* b1   = (const float*)d_in[5];
  const float* W2   = (const float*)d_in[6];
  const float* b2   = (const float*)d_in[7];
  const float* cw   = (const float*)d_in[8];
  const float* bias = (const float*)d_in[9];

  char* ws = (char*)d_ws;
  __bf16* q_bf  = (__bf16*)(ws);                               // 32 MB, reused as Y
  __bf16* w1_bf = (__bf16*)(ws + (32u << 20));                 // 4 MB
  __bf16* w2_bf = (__bf16*)(ws + (36u << 20));                 // 2 MB
  float*  swm   = (float*)(ws + (38u << 20));                  // 496 B
  __bf16* x1    = (__bf16*)d_out;  // (B,T,2C) bf16 = exactly 64 MB, freed before GEMM2
  __bf16* y_bf  = q_bf;            // reuse q region after GEMM1

  cvt_bf16_kernel<<<2048, 256, 0, stream>>>(q, q_bf, 16 * 1024 * 1024 / 4);
  cvt_bf16_kernel<<<512, 256, 0, stream>>>(W1, w1_bf, 2048 * 1024 / 4);
  cvt_bf16_kernel<<<256, 256, 0, stream>>>(W2, w2_bf, 1024 * 1024 / 4);
  softmax_w_kernel<<<1, 64, 0, stream>>>(cw, swm);

  // GEMM1 + b1 -> x1 (bf16, in d_out)
  gemm_bt_kernel<1><<<dim3(16, 128), 256, 0, stream>>>(q_bf, w1_bf, b1, (void*)x1,
                                                       16384, 2048, 1024);
  // GLU + conv + bias + mask -> y (bf16, in ws)
  glu_conv_kernel<<<dim3(8, 16, 16), 256, 0, stream>>>(x1, swm, bias, mask, y_bf);
  // GEMM2 + b2 -> d_out (f32)
  gemm_bt_kernel<0><<<dim3(8, 128), 256, 0, stream>>>(y_bf, w2_bf, b2, d_out,
                                                      16384, 1024, 1024);
}

// Round 2
// 227.110 us; speedup vs baseline: 1.0684x; 1.0684x over previous
//
#include <hip/hip_runtime.h>

typedef __attribute__((ext_vector_type(8))) __bf16 bf16x8;
typedef __attribute__((ext_vector_type(4))) __bf16 bf16x4;
typedef __attribute__((ext_vector_type(4))) float  f32x4;
typedef __attribute__((ext_vector_type(4))) float  float4v;

#define DEV static __device__ __forceinline__

DEV void gload_lds16(const void* g, void* l) {
  __builtin_amdgcn_global_load_lds(
      (const __attribute__((address_space(1))) void*)g,
      (__attribute__((address_space(3))) void*)l, 16, 0, 0);
}

// ---------------- f32 -> bf16 convert (vectorized) ----------------
__global__ void cvt_bf16_kernel(const float* __restrict__ in,
                                __bf16* __restrict__ out, int n4) {
  int stride = gridDim.x * blockDim.x;
  for (int i = blockIdx.x * blockDim.x + threadIdx.x; i < n4; i += stride) {
    float4v v = ((const float4v*)in)[i];
    bf16x4 o;
#pragma unroll
    for (int j = 0; j < 4; ++j) o[j] = (__bf16)v[j];
    ((bf16x4*)out)[i] = o;
  }
}

// ---------------- softmax of conv_w (H=4, K=31) ----------------
__global__ void softmax_w_kernel(const float* __restrict__ cw,
                                 float* __restrict__ out) {
  int h = threadIdx.x;
  if (h < 4) {
    float m = cw[h * 31];
#pragma unroll
    for (int k = 1; k < 31; ++k) m = fmaxf(m, cw[h * 31 + k]);
    float e[31];
    float s = 0.f;
#pragma unroll
    for (int k = 0; k < 31; ++k) {
      e[k] = __expf(cw[h * 31 + k] - m);
      s += e[k];
    }
    float inv = 1.f / s;
#pragma unroll
    for (int k = 0; k < 31; ++k) out[h * 31 + k] = e[k] * inv;
  }
}

// ===================== 256x256 8-phase GEMM (T1+T2+T3+T4+T5) =====================
// C[M][N] = A[M][K] * Bw[N][K]^T + bias[N].
// 512 threads = 8 waves (2M x 4N). BK=64 split into two K-half granules [256][32].
// LDS: 2 dbuf x 2 khalf x (256x32) bf16 for each of A,B = 128 KiB.
// Per K-tile: 4 phases {ds_read, stage 1 granule of tile t+1, barrier,
// lgkmcnt(0), 16 MFMA, [vmcnt(4) on odd phases], barrier}.
// Swizzle: LDS physical byte p holds logical p ^ ((p>>9)&1)<<5 within each
// 16KB granule (linear gload_lds dest + pre-swizzled global src; swizzled read).
template <int STORE_BF16>
__global__ __launch_bounds__(512, 2)
void gemm256_kernel(const __bf16* __restrict__ A, const __bf16* __restrict__ Bw,
                    const float* __restrict__ bias, void* __restrict__ Cout,
                    int M, int N, int K, int ntn) {
  __shared__ __align__(16) __bf16 Al[2 * 2 * 8192];  // [dbuf][khalf][256*32]
  __shared__ __align__(16) __bf16 Bl[2 * 2 * 8192];

  const int tid  = threadIdx.x;
  const int lane = tid & 63;
  const int w    = tid >> 6;
  const int wm = w >> 2, wn = w & 3;

  // T1: XCD-aware bijective swizzle (gridDim.x % 8 == 0 for both GEMMs)
  const int nwg = gridDim.x;
  const int cpx = nwg >> 3;
  const int bid = blockIdx.x;
  const int wgid = (bid & 7) * cpx + (bid >> 3);
  const int m0 = (wgid / ntn) * 256;
  const int n0 = (wgid % ntn) * 256;

  const int NT = K >> 6;

  // staging per-lane source offsets (swizzle folded: XOR term is lane-const)
  const int srow = lane >> 2;                                   // row in 16-row slice
  const int scol = ((lane & 3) * 8) ^ (((lane >> 5) & 1) * 16); // elems
  const __bf16* __restrict__ Abase = A + (long)m0 * K;
  const __bf16* __restrict__ Bbase = Bw + (long)n0 * K;

  // ds_read per-lane offsets (swizzle folded likewise)
  const int l15 = lane & 15;
  const int cb  = ((lane >> 4) * 16) ^ (((lane >> 3) & 1) * 32);  // bytes
  const int aoff = (wm * 128 + l15) * 64 + cb;  // + i*1024
  const int boff = (wn * 64 + l15) * 64 + cb;   // + j*1024

  f32x4 acc[8][4];
#pragma unroll
  for (int i = 0; i < 8; ++i)
#pragma unroll
    for (int j = 0; j < 4; ++j) {
      acc[i][j][0] = 0.f; acc[i][j][1] = 0.f;
      acc[i][j][2] = 0.f; acc[i][j][3] = 0.f;
    }
  bf16x8 af[8], bf[4];

#define ADST(c, s) (Al + (c) * 16384 + (s) * 8192)
#define BDST(c, s) (Bl + (c) * 16384 + (s) * 8192)
#define AG(c, s) ((const char*)Al + (c) * 32768 + (s) * 16384)
#define BG(c, s) ((const char*)Bl + (c) * 32768 + (s) * 16384)

  // stage one granule (one matrix, one k-half): 2 gload_lds per wave
#define STAGE(base, ktc, dst)                                              \
  {                                                                        \
    const __bf16* _src = (base) + (long)(w * 16 + srow) * K + (ktc) + scol; \
    gload_lds16(_src, (dst) + w * 512);                                    \
    gload_lds16(_src + (long)128 * K, (dst) + 4096 + w * 512);             \
  }

#define PH_MID()                                          \
  __builtin_amdgcn_s_barrier();                           \
  asm volatile("s_waitcnt lgkmcnt(0)" ::: "memory");      \
  __builtin_amdgcn_sched_barrier(0);                      \
  __builtin_amdgcn_s_setprio(1);

#define PH_END(VM)                                        \
  __builtin_amdgcn_s_setprio(0);                          \
  if (VM) asm volatile("s_waitcnt vmcnt(4)" ::: "memory"); \
  __builtin_amdgcn_s_barrier();

#define MFMA_J01()                                                         \
  _Pragma("unroll") for (int i = 0; i < 8; ++i) {                          \
    acc[i][0] = __builtin_amdgcn_mfma_f32_16x16x32_bf16(af[i], bf[0], acc[i][0], 0, 0, 0); \
    acc[i][1] = __builtin_amdgcn_mfma_f32_16x16x32_bf16(af[i], bf[1], acc[i][1], 0, 0, 0); \
  }
#define MFMA_J23()                                                         \
  _Pragma("unroll") for (int i = 0; i < 8; ++i) {                          \
    acc[i][2] = __builtin_amdgcn_mfma_f32_16x16x32_bf16(af[i], bf[2], acc[i][2], 0, 0, 0); \
    acc[i][3] = __builtin_amdgcn_mfma_f32_16x16x32_bf16(af[i], bf[3], acc[i][3], 0, 0, 0); \
  }

  // ---- prologue: stage tile 0 (A-kh0, B-kh0, A-kh1, B-kh1), wait first 4 ----
  STAGE(Abase, 0, ADST(0, 0));
  STAGE(Bbase, 0, BDST(0, 0));
  STAGE(Abase, 32, ADST(0, 1));
  STAGE(Bbase, 32, BDST(0, 1));
  asm volatile("s_waitcnt vmcnt(4)" ::: "memory");
  __builtin_amdgcn_s_barrier();

  // one K-tile = 4 phases; CUR is compile-time (loop manually 2x unrolled)
#define TILE(tt, CUR)                                                      \
  {                                                                        \
    const int ktn = (((tt) + 1 < NT) ? ((tt) + 1) : (NT - 1)) << 6;        \
    /* ph0: read A s0 (8), B j0-1 s0 (2); stage A-kh0(t+1) */              \
    _Pragma("unroll") for (int i = 0; i < 8; ++i)                          \
        af[i] = *(const bf16x8*)(AG(CUR, 0) + aoff + i * 1024);            \
    bf[0] = *(const bf16x8*)(BG(CUR, 0) + boff);                           \
    bf[1] = *(const bf16x8*)(BG(CUR, 0) + boff + 1024);                    \
    STAGE(Abase, ktn, ADST(CUR ^ 1, 0));                                   \
    PH_MID(); MFMA_J01(); PH_END(0);                                       \
    /* ph1: read B j2-3 s0 (2); stage B-kh0(t+1); vmcnt(4) */              \
    bf[2] = *(const bf16x8*)(BG(CUR, 0) + boff + 2048);                    \
    bf[3] = *(const bf16x8*)(BG(CUR, 0) + boff + 3072);                    \
    STAGE(Bbase, ktn, BDST(CUR ^ 1, 0));                                   \
    PH_MID(); MFMA_J23(); PH_END(1);                                       \
    /* ph2: read A s1 (8), B j0-1 s1 (2); stage A-kh1(t+1) */              \
    _Pragma("unroll") for (int i = 0; i < 8; ++i)                          \
        af[i] = *(const bf16x8*)(AG(CUR, 1) + aoff + i * 1024);            \
    bf[0] = *(const bf16x8*)(BG(CUR, 1) + boff);                           \
    bf[1] = *(const bf16x8*)(BG(CUR, 1) + boff + 1024);                    \
    STAGE(Abase, ktn + 32, ADST(CUR ^ 1, 1));                              \
    PH_MID(); MFMA_J01(); PH_END(0);                                       \
    /* ph3: read B j2-3 s1 (2); stage B-kh1(t+1); vmcnt(4) */              \
    bf[2] = *(const bf16x8*)(BG(CUR, 1) + boff + 2048);                    \
    bf[3] = *(const bf16x8*)(BG(CUR, 1) + boff + 3072);                    \
    STAGE(Bbase, ktn + 32, BDST(CUR ^ 1, 1));                              \
    PH_MID(); MFMA_J23(); PH_END(1);                                       \
  }

#pragma unroll 1
  for (int t2 = 0; t2 < NT; t2 += 2) {
    TILE(t2, 0);
    TILE(t2 + 1, 1);
  }

  // ---- epilogue: C/D layout col=lane&15, row=(lane>>4)*4+reg ----
  const int crow = (lane >> 4) * 4;
  const int ccol = lane & 15;
#pragma unroll
  for (int i = 0; i < 8; ++i) {
#pragma unroll
    for (int j = 0; j < 4; ++j) {
      const int mrow = m0 + wm * 128 + i * 16 + crow;
      const int ncol = n0 + wn * 64 + j * 16 + ccol;
      const float bv = bias[ncol];
#pragma unroll
      for (int r = 0; r < 4; ++r) {
        float v = acc[i][j][r] + bv;
        if (STORE_BF16)
          ((__bf16*)Cout)[(long)(mrow + r) * N + ncol] = (__bf16)v;
        else
          ((float*)Cout)[(long)(mrow + r) * N + ncol] = v;
      }
    }
  }
#undef TILE
#undef STAGE
#undef PH_MID
#undef PH_END
#undef MFMA_J01
#undef MFMA_J23
#undef ADST
#undef BDST
#undef AG
#undef BG
}

// ------- fused GLU + depthwise conv (K=31, pad 15) + bias + mask -------
__global__ __launch_bounds__(256, 2)
void glu_conv_kernel(const __bf16* __restrict__ X, const float* __restrict__ Wsm,
                     const float* __restrict__ bias, const int* __restrict__ mask,
                     __bf16* __restrict__ Y) {
  const int b  = blockIdx.z;
  const int t0 = blockIdx.y * 64;
  const int c0 = blockIdx.x * 128;
  __shared__ float sg[94][128];  // t0-15 .. t0+78
  __shared__ float sw[4][31];
  const int tid = threadIdx.x;
  if (tid < 124) ((float*)sw)[tid] = Wsm[tid];
  for (int i = tid; i < 94 * 128; i += 256) {
    const int tt = i >> 7, cc = i & 127;
    const int t = t0 - 15 + tt;
    float v = 0.f;
    if (t >= 0 && t < 1024) {
      const long base = ((long)b * 1024 + t) * 2048 + c0 + cc;
      const float a = (float)X[base];
      const float g = (float)X[base + 1024];
      v = a / (1.f + __expf(-g));  // a * sigmoid(g)
    }
    sg[tt][cc] = v;
  }
  __syncthreads();
  const int cc = tid & 127;
  const int th = tid >> 7;
  const int c  = c0 + cc;
  const float bv = bias[c];
  const float* wrow = sw[c & 3];
  for (int tt = 0; tt < 32; ++tt) {
    const int t = th * 32 + tt;
    float s = bv;
#pragma unroll
    for (int k = 0; k < 31; ++k) s += sg[t + k][cc] * wrow[k];
    const int gt = t0 + t;
    if (mask[b * 1024 + gt] == 0) s = 0.f;
    Y[((long)b * 1024 + gt) * 1024 + c] = (__bf16)s;
  }
}

extern "C" void kernel_launch(void* const* d_in, const int* in_sizes, int n_in,
                              void* d_out, int out_size, void* d_ws, size_t ws_size,
                              hipStream_t stream) {
  const float* q    = (const float*)d_in[0];
  const int*   mask = (const int*)d_in[3];
  const float* W1   = (const float*)d_in[4];
  const float* b1   = (const float*)d_in[5];
  const float* W2   = (const float*)d_in[6];
  const float* b2   = (const float*)d_in[7];
  const float* cw   = (const float*)d_in[8];
  const float* bias = (const float*)d_in[9];

  char* ws = (char*)d_ws;
  __bf16* q_bf  = (__bf16*)(ws);                // 32 MB, reused as Y
  __bf16* w1_bf = (__bf16*)(ws + (32u << 20));  // 4 MB
  __bf16* w2_bf = (__bf16*)(ws + (36u << 20));  // 2 MB
  float*  swm   = (float*)(ws + (38u << 20));   // 496 B
  __bf16* x1    = (__bf16*)d_out;  // (B,T,2C) bf16 = 64 MB, freed before GEMM2
  __bf16* y_bf  = q_bf;

  cvt_bf16_kernel<<<2048, 256, 0, stream>>>(q, q_bf, 16 * 1024 * 1024 / 4);
  cvt_bf16_kernel<<<512, 256, 0, stream>>>(W1, w1_bf, 2048 * 1024 / 4);
  cvt_bf16_kernel<<<256, 256, 0, stream>>>(W2, w2_bf, 1024 * 1024 / 4);
  softmax_w_kernel<<<1, 64, 0, stream>>>(cw, swm);

  // GEMM1 + b1 -> x1 (bf16): grid 64x8 = 512 blocks
  gemm256_kernel<1><<<512, 512, 0, stream>>>(q_bf, w1_bf, b1, (void*)x1,
                                             16384, 2048, 1024, 8);
  // GLU + conv + bias + mask -> y (bf16)
  glu_conv_kernel<<<dim3(8, 16, 16), 256, 0, stream>>>(x1, swm, bias, mask, y_bf);
  // GEMM2 + b2 -> d_out (f32): grid 64x4 = 256 blocks
  gemm256_kernel<0><<<256, 512, 0, stream>>>(y_bf, w2_bf, b2, d_out,
                                             16384, 1024, 1024, 4);
}

// Round 3
// 190.559 us; speedup vs baseline: 1.2734x; 1.1918x over previous
//
#include <hip/hip_runtime.h>

typedef __attribute__((ext_vector_type(8))) __bf16 bf16x8;
typedef __attribute__((ext_vector_type(4))) __bf16 bf16x4;
typedef __attribute__((ext_vector_type(4))) float  f32x4;
typedef __attribute__((ext_vector_type(4))) float  float4v;

#define DEV static __device__ __forceinline__

DEV void gload_lds16(const void* g, void* l) {
  __builtin_amdgcn_global_load_lds(
      (const __attribute__((address_space(1))) void*)g,
      (__attribute__((address_space(3))) void*)l, 16, 0, 0);
}

// ---------------- f32 -> bf16 convert (vectorized) ----------------
__global__ void cvt_bf16_kernel(const float* __restrict__ in,
                                __bf16* __restrict__ out, int n4) {
  int stride = gridDim.x * blockDim.x;
  for (int i = blockIdx.x * blockDim.x + threadIdx.x; i < n4; i += stride) {
    float4v v = ((const float4v*)in)[i];
    bf16x4 o;
#pragma unroll
    for (int j = 0; j < 4; ++j) o[j] = (__bf16)v[j];
    ((bf16x4*)out)[i] = o;
  }
}

// ---------------- softmax of conv_w (H=4, K=31) ----------------
__global__ void softmax_w_kernel(const float* __restrict__ cw,
                                 float* __restrict__ out) {
  int h = threadIdx.x;
  if (h < 4) {
    float m = cw[h * 31];
#pragma unroll
    for (int k = 1; k < 31; ++k) m = fmaxf(m, cw[h * 31 + k]);
    float e[31];
    float s = 0.f;
#pragma unroll
    for (int k = 0; k < 31; ++k) {
      e[k] = __expf(cw[h * 31 + k] - m);
      s += e[k];
    }
    float inv = 1.f / s;
#pragma unroll
    for (int k = 0; k < 31; ++k) out[h * 31 + k] = e[k] * inv;
  }
}

// ===================== 256x256 8-phase GEMM, deep prefetch =====================
// C[M][N] = A[M][K] * Bw[N][K]^T + bias[N].
// 512 threads = 8 waves (2M x 4N). BK=64 as two K-half granules [256][32].
// Slots per matrix: [2 parity][2 khalf] x 16KB. Granule (c,kh0) is dead after
// ph1, (c,kh1) after ph3 -> stage t+1 kh1 at ph0/ph1, t+2 kh0 at ph2/ph3.
// vmcnt(8) at ph1/ph3 end: 4 granules stay in flight, issue->wait slack 4-5
// phases. Swizzle: phys byte p holds logical p ^ (((p>>9)&1)<<5) per granule.
template <int STORE_BF16>
__global__ __launch_bounds__(512, 2)
void gemm256_kernel(const __bf16* __restrict__ A, const __bf16* __restrict__ Bw,
                    const float* __restrict__ bias, void* __restrict__ Cout,
                    int M, int N, int K, int ntn) {
  __shared__ __align__(16) __bf16 Al[4 * 8192];  // [parity*2+khalf][256*32]
  __shared__ __align__(16) __bf16 Bl[4 * 8192];

  const int tid  = threadIdx.x;
  const int lane = tid & 63;
  const int w    = tid >> 6;
  const int wm = w >> 2, wn = w & 3;

  // T1: XCD-aware bijective swizzle (grid % 8 == 0 for both GEMMs)
  const int nwg = gridDim.x;
  const int cpx = nwg >> 3;
  const int bid = blockIdx.x;
  const int wgid = (bid & 7) * cpx + (bid >> 3);
  const int m0 = (wgid / ntn) * 256;
  const int n0 = (wgid % ntn) * 256;

  const int NT = K >> 6;  // requires NT >= 2, even

  const int srow = lane >> 2;
  const int scol = ((lane & 3) * 8) ^ (((lane >> 5) & 1) * 16);
  const __bf16* __restrict__ Abase = A + (long)m0 * K;
  const __bf16* __restrict__ Bbase = Bw + (long)n0 * K;

  const int l15 = lane & 15;
  const int cb  = ((lane >> 4) * 16) ^ (((lane >> 3) & 1) * 32);
  const int aoff = (wm * 128 + l15) * 64 + cb;
  const int boff = (wn * 64 + l15) * 64 + cb;

  f32x4 acc[8][4];
#pragma unroll
  for (int i = 0; i < 8; ++i)
#pragma unroll
    for (int j = 0; j < 4; ++j) {
      acc[i][j][0] = 0.f; acc[i][j][1] = 0.f;
      acc[i][j][2] = 0.f; acc[i][j][3] = 0.f;
    }
  bf16x8 af[8], bf[4];

#define ADST(c, s) (Al + ((c) * 2 + (s)) * 8192)
#define BDST(c, s) (Bl + ((c) * 2 + (s)) * 8192)
#define AGB(c, s) ((const char*)Al + ((c) * 2 + (s)) * 16384)
#define BGB(c, s) ((const char*)Bl + ((c) * 2 + (s)) * 16384)

#define STAGE(base, ktc, dst)                                               \
  {                                                                         \
    const __bf16* _src = (base) + (long)(w * 16 + srow) * K + (ktc) + scol; \
    gload_lds16(_src, (dst) + w * 512);                                     \
    gload_lds16(_src + (long)128 * K, (dst) + 4096 + w * 512);              \
  }

#define PH_MID()                                          \
  __builtin_amdgcn_s_barrier();                           \
  asm volatile("s_waitcnt lgkmcnt(0)" ::: "memory");      \
  __builtin_amdgcn_sched_barrier(0);                      \
  __builtin_amdgcn_s_setprio(1);

#define PH_END(VM)                                          \
  __builtin_amdgcn_s_setprio(0);                            \
  if (VM) asm volatile("s_waitcnt vmcnt(8)" ::: "memory");  \
  __builtin_amdgcn_s_barrier();

#define RD_A03(G)                                                  \
  _Pragma("unroll") for (int i = 0; i < 4; ++i)                    \
      af[i] = *(const bf16x8*)((G) + aoff + i * 1024);
#define RD_A47(G)                                                  \
  _Pragma("unroll") for (int i = 0; i < 4; ++i)                    \
      af[4 + i] = *(const bf16x8*)((G) + aoff + (4 + i) * 1024);
#define RD_B4(G)                                                   \
  _Pragma("unroll") for (int j = 0; j < 4; ++j)                    \
      bf[j] = *(const bf16x8*)((G) + boff + j * 1024);

#define MM03()                                                                 \
  _Pragma("unroll") for (int i = 0; i < 4; ++i)                                \
  _Pragma("unroll") for (int j = 0; j < 4; ++j)                                \
      acc[i][j] = __builtin_amdgcn_mfma_f32_16x16x32_bf16(af[i], bf[j], acc[i][j], 0, 0, 0);
#define MM47()                                                                 \
  _Pragma("unroll") for (int i = 0; i < 4; ++i)                                \
  _Pragma("unroll") for (int j = 0; j < 4; ++j)                                \
      acc[4 + i][j] = __builtin_amdgcn_mfma_f32_16x16x32_bf16(af[4 + i], bf[j], acc[4 + i][j], 0, 0, 0);

  // ---- prologue: tile0 (kh0,kh1) + tile1 kh0; wait first 2 granules ----
  STAGE(Abase, 0, ADST(0, 0));
  STAGE(Bbase, 0, BDST(0, 0));
  STAGE(Abase, 32, ADST(0, 1));
  STAGE(Bbase, 32, BDST(0, 1));
  STAGE(Abase, 64, ADST(1, 0));
  STAGE(Bbase, 64, BDST(1, 0));
  asm volatile("s_waitcnt vmcnt(8)" ::: "memory");
  __builtin_amdgcn_s_barrier();

#define TILE(tt, CUR)                                                \
  {                                                                  \
    const int k1 = (((tt) + 1 < NT) ? (tt) + 1 : NT - 1) * 64 + 32;  \
    const int k2 = (((tt) + 2 < NT) ? (tt) + 2 : NT - 1) * 64;       \
    /* ph0 */                                                        \
    RD_A03(AGB(CUR, 0)); RD_B4(BGB(CUR, 0));                         \
    STAGE(Abase, k1, ADST(CUR ^ 1, 1));                              \
    PH_MID(); MM03(); PH_END(0);                                     \
    /* ph1 */                                                        \
    RD_A47(AGB(CUR, 0));                                             \
    STAGE(Bbase, k1, BDST(CUR ^ 1, 1));                              \
    PH_MID(); MM47(); PH_END(1);                                     \
    /* ph2 */                                                        \
    RD_A03(AGB(CUR, 1)); RD_B4(BGB(CUR, 1));                         \
    STAGE(Abase, k2, ADST(CUR, 0));                                  \
    PH_MID(); MM03(); PH_END(0);                                     \
    /* ph3 */                                                        \
    RD_A47(AGB(CUR, 1));                                             \
    STAGE(Bbase, k2, BDST(CUR, 0));                                  \
    PH_MID(); MM47(); PH_END(1);                                     \
  }

#pragma unroll 1
  for (int t2 = 0; t2 < NT; t2 += 2) {
    TILE(t2, 0);
    TILE(t2 + 1, 1);
  }

  // drain pending global_load_lds before LDS can be re-allocated to next block
  asm volatile("s_waitcnt vmcnt(0)" ::: "memory");

  // ---- epilogue: C/D layout col=lane&15, row=(lane>>4)*4+reg ----
  const int crow = (lane >> 4) * 4;
  const int ccol = lane & 15;
#pragma unroll
  for (int i = 0; i < 8; ++i) {
#pragma unroll
    for (int j = 0; j < 4; ++j) {
      const int mrow = m0 + wm * 128 + i * 16 + crow;
      const int ncol = n0 + wn * 64 + j * 16 + ccol;
      const float bv = bias[ncol];
#pragma unroll
      for (int r = 0; r < 4; ++r) {
        float v = acc[i][j][r] + bv;
        if (STORE_BF16)
          ((__bf16*)Cout)[(long)(mrow + r) * N + ncol] = (__bf16)v;
        else
          ((float*)Cout)[(long)(mrow + r) * N + ncol] = v;
      }
    }
  }
#undef TILE
#undef STAGE
#undef PH_MID
#undef PH_END
#undef RD_A03
#undef RD_A47
#undef RD_B4
#undef MM03
#undef MM47
#undef ADST
#undef BDST
#undef AGB
#undef BGB
}

// ------- fused GLU + depthwise conv (K=31, pad 15) + bias + mask -------
// Tap-major transposed LDS: sgT[128 ch][32 quads x4] with XOR quad swizzle.
// Block tile: 64 t x 128 c. Reads: 16 b128/thread, 8-addr broadcast
// (conflict-free). Writes: ~2-way. Stencil streamed through registers.
__global__ __launch_bounds__(256, 2)
void glu_conv_kernel(const __bf16* __restrict__ X, const float* __restrict__ Wsm,
                     const float* __restrict__ bias, const int* __restrict__ mask,
                     __bf16* __restrict__ Y) {
  const int b  = blockIdx.z;
  const int t0 = blockIdx.y * 64;
  const int c0 = blockIdx.x * 128;
  __shared__ float sgT[128][128];  // [channel][ (quad^key)<<2 + elem ], 64KB
  __shared__ float swl[124];
  const int tid = threadIdx.x;
  if (tid < 124) swl[tid] = Wsm[tid];

  // GLU phase: lane index spans taps -> LDS writes ~2-way conflict
  for (int i = tid; i < 2048; i += 256) {
    const int ttl = i & 127;  // tap 0..127 (94 used)
    const int cg  = i >> 7;   // channel octet 0..15
    if (ttl < 94) {
      const int t = t0 - 15 + ttl;
      float v[8];
      if (t >= 0 && t < 1024) {
        const __bf16* p = X + ((long)(b * 1024 + t)) * 2048 + c0 + cg * 8;
        bf16x8 a8 = *(const bf16x8*)p;
        bf16x8 g8 = *(const bf16x8*)(p + 1024);
#pragma unroll
        for (int j = 0; j < 8; ++j) {
          float av = (float)a8[j], gv = (float)g8[j];
          v[j] = av / (1.f + __expf(-gv));
        }
      } else {
#pragma unroll
        for (int j = 0; j < 8; ++j) v[j] = 0.f;
      }
      const int q = ttl >> 2, e = ttl & 3;
#pragma unroll
      for (int j = 0; j < 8; ++j) {
        const int c = cg * 8 + j;
        sgT[c][((q ^ ((c & 7) << 2)) << 2) + e] = v[j];
      }
    }
  }
  __syncthreads();

  // conv phase: thread = (channel cc, half th), 32 consecutive outputs
  const int cc = tid & 127;
  const int th = tid >> 7;
  const int c  = c0 + cc;
  const float* wrow = swl + (c & 3) * 31;
  const float bv = bias[c];
  float acc[32];
#pragma unroll
  for (int u = 0; u < 32; ++u) acc[u] = bv;
  const int key = (cc & 7) << 2;
#pragma unroll
  for (int qi = 0; qi < 16; ++qi) {
    const int q = th * 8 + qi;
    const f32x4 w4 = *(const f32x4*)&sgT[cc][(q ^ key) << 2];
#pragma unroll
    for (int j = 0; j < 4; ++j) {
      const int rl = qi * 4 + j;  // tap index relative to th*32
#pragma unroll
      for (int u = 0; u < 32; ++u) {
        const int k = rl - u;
        if (k >= 0 && k < 31) acc[u] += w4[j] * wrow[k];
      }
    }
  }
  const long yb = (long)b * 1024 * 1024;
#pragma unroll
  for (int u = 0; u < 32; ++u) {
    const int gt = t0 + th * 32 + u;
    float v = acc[u];
    if (mask[b * 1024 + gt] == 0) v = 0.f;
    Y[yb + (long)gt * 1024 + c] = (__bf16)v;
  }
}

extern "C" void kernel_launch(void* const* d_in, const int* in_sizes, int n_in,
                              void* d_out, int out_size, void* d_ws, size_t ws_size,
                              hipStream_t stream) {
  const float* q    = (const float*)d_in[0];
  const int*   mask = (const int*)d_in[3];
  const float* W1   = (const float*)d_in[4];
  const float* b1   = (const float*)d_in[5];
  const float* W2   = (const float*)d_in[6];
  const float* b2   = (const float*)d_in[7];
  const float* cw   = (const float*)d_in[8];
  const float* bias = (const float*)d_in[9];

  char* ws = (char*)d_ws;
  __bf16* q_bf  = (__bf16*)(ws);                // 32 MB, reused as Y
  __bf16* w1_bf = (__bf16*)(ws + (32u << 20));  // 4 MB
  __bf16* w2_bf = (__bf16*)(ws + (36u << 20));  // 2 MB
  float*  swm   = (float*)(ws + (38u << 20));   // 496 B
  __bf16* x1    = (__bf16*)d_out;  // (B,T,2C) bf16 = 64 MB, freed before GEMM2
  __bf16* y_bf  = q_bf;

  cvt_bf16_kernel<<<2048, 256, 0, stream>>>(q, q_bf, 16 * 1024 * 1024 / 4);
  cvt_bf16_kernel<<<512, 256, 0, stream>>>(W1, w1_bf, 2048 * 1024 / 4);
  cvt_bf16_kernel<<<256, 256, 0, stream>>>(W2, w2_bf, 1024 * 1024 / 4);
  softmax_w_kernel<<<1, 64, 0, stream>>>(cw, swm);

  // GEMM1 + b1 -> x1 (bf16): grid 64x8 = 512 blocks
  gemm256_kernel<1><<<512, 512, 0, stream>>>(q_bf, w1_bf, b1, (void*)x1,
                                             16384, 2048, 1024, 8);
  // GLU + conv + bias + mask -> y (bf16)
  glu_conv_kernel<<<dim3(8, 16, 16), 256, 0, stream>>>(x1, swm, bias, mask, y_bf);
  // GEMM2 + b2 -> d_out (f32): grid 64x4 = 256 blocks
  gemm256_kernel<0><<<256, 512, 0, stream>>>(y_bf, w2_bf, b2, d_out,
                                             16384, 1024, 1024, 4);
}

// Round 4
// 186.079 us; speedup vs baseline: 1.3040x; 1.0241x over previous
//
#include <hip/hip_runtime.h>

typedef __attribute__((ext_vector_type(8))) __bf16 bf16x8;
typedef __attribute__((ext_vector_type(4))) __bf16 bf16x4;
typedef __attribute__((ext_vector_type(4))) float  f32x4;
typedef __attribute__((ext_vector_type(4))) float  float4v;

#define DEV static __device__ __forceinline__

DEV void gload_lds16(const void* g, void* l) {
  __builtin_amdgcn_global_load_lds(
      (const __attribute__((address_space(1))) void*)g,
      (__attribute__((address_space(3))) void*)l, 16, 0, 0);
}

// ---------------- f32 -> bf16 convert (vectorized) ----------------
__global__ void cvt_bf16_kernel(const float* __restrict__ in,
                                __bf16* __restrict__ out, int n4) {
  int stride = gridDim.x * blockDim.x;
  for (int i = blockIdx.x * blockDim.x + threadIdx.x; i < n4; i += stride) {
    float4v v = ((const float4v*)in)[i];
    bf16x4 o;
#pragma unroll
    for (int j = 0; j < 4; ++j) o[j] = (__bf16)v[j];
    ((bf16x4*)out)[i] = o;
  }
}

// ---------------- softmax of conv_w (H=4, K=31) ----------------
__global__ void softmax_w_kernel(const float* __restrict__ cw,
                                 float* __restrict__ out) {
  int h = threadIdx.x;
  if (h < 4) {
    float m = cw[h * 31];
#pragma unroll
    for (int k = 1; k < 31; ++k) m = fmaxf(m, cw[h * 31 + k]);
    float e[31];
    float s = 0.f;
#pragma unroll
    for (int k = 0; k < 31; ++k) {
      e[k] = __expf(cw[h * 31 + k] - m);
      s += e[k];
    }
    float inv = 1.f / s;
#pragma unroll
    for (int k = 0; k < 31; ++k) out[h * 31 + k] = e[k] * inv;
  }
}

// ============ 256x256 8-phase GEMM, full-cache-line granules ============
// C[M][N] = A[M][K] * Bw[N][K]^T + bias[N].
// 512 threads = 8 waves (2M x 4N). Granule = [128 rows][BK=64] bf16 = 16KB,
// rows are FULL 128B cache lines (staging lanes tile whole lines).
// Slots: A[parity][mhalf], B[parity][nhalf]; each wave reads one A granule
// (its wm) and one B granule (its wn>>1) per tile.
// Phases: ph0 {rd A(i0-3,kk01)+B(j0-1,kk01); stage A(t+1) both mh} MFMA i0-3xj0-1
//         ph1 {rd B(j2-3); stage B(t+1) both nh}                   MFMA i0-3xj2-3
//         ph2 {rd A(i4-7)}                          vmcnt(4)       MFMA i4-7xj0-1
//         ph3 {}                                    vmcnt(0)       MFMA i4-7xj2-3
// LDS swizzle: phys byte (within granule) = row*128 + (cb ^ ((row&7)<<4));
// linear gload_lds dest + inverse-swizzled per-lane GLOBAL source (rule 21).
template <int STORE_BF16>
__global__ __launch_bounds__(512, 2)
void gemm256_kernel(const __bf16* __restrict__ A, const __bf16* __restrict__ Bw,
                    const float* __restrict__ bias, void* __restrict__ Cout,
                    int M, int N, int K, int ntn) {
  __shared__ __align__(16) __bf16 Al[4 * 8192];  // [parity*2+mhalf][128*64]
  __shared__ __align__(16) __bf16 Bl[4 * 8192];  // [parity*2+nhalf][128*64]

  const int tid  = threadIdx.x;
  const int lane = tid & 63;
  const int w    = tid >> 6;
  const int wm = w >> 2, wn = w & 3;

  // T1: XCD-aware bijective swizzle (grid % 8 == 0 for both GEMMs)
  const int nwg = gridDim.x;
  const int cpx = nwg >> 3;
  const int bid = blockIdx.x;
  const int wgid = (bid & 7) * cpx + (bid >> 3);
  const int m0 = (wgid / ntn) * 256;
  const int n0 = (wgid % ntn) * 256;

  const int NT = K >> 6;  // even, >= 2

  // staging: thread covers 16B at phys (row = L*64 + tid>>3, cb = (tid&7)*16);
  // inverse-swizzled global column (elems), per-thread constant:
  const int scolE = ((((tid & 7) * 16) ^ (((tid >> 3) & 7) << 4)) >> 1);
  const __bf16* __restrict__ Abase = A + (long)m0 * K;
  const __bf16* __restrict__ Bbase = Bw + (long)n0 * K;

  // ds_read offsets (bytes within granule), swizzled:
  const int l15 = lane & 15;
  const int xk  = (l15 & 7) << 4;
  const int a0  = l15 * 128 + (((lane >> 4) * 16) ^ xk);         // kk=0
  const int a1  = l15 * 128 + ((((lane >> 4) * 16) + 64) ^ xk);  // kk=1
  const int bq  = (wn & 1) * 8192;  // n-quarter offset inside B granule
  const int b0  = bq + a0;
  const int b1  = bq + a1;

  f32x4 acc[8][4];
#pragma unroll
  for (int i = 0; i < 8; ++i)
#pragma unroll
    for (int j = 0; j < 4; ++j) {
      acc[i][j][0] = 0.f; acc[i][j][1] = 0.f;
      acc[i][j][2] = 0.f; acc[i][j][3] = 0.f;
    }
  bf16x8 af[8], bf[8];

#define ADST(p, mh) (Al + ((p) * 2 + (mh)) * 8192)
#define BDST(p, nh) (Bl + ((p) * 2 + (nh)) * 8192)
#define AWG(p) ((const char*)Al + ((p) * 2 + wm) * 16384)
#define BWG(p) ((const char*)Bl + ((p) * 2 + (wn >> 1)) * 16384)

// stage one [128][64] granule: 2 gload_lds/thread, full 128B lines
#define STAGEG(base, groff, ktc, dst)                                         \
  {                                                                           \
    const __bf16* _s = (base) + (long)((groff) + (tid >> 3)) * K + (ktc) + scolE; \
    gload_lds16(_s, (dst) + tid * 8);                                         \
    gload_lds16(_s + (long)64 * K, (dst) + 4096 + tid * 8);                   \
  }

#define PH_MID()                                     \
  __builtin_amdgcn_s_barrier();                      \
  asm volatile("s_waitcnt lgkmcnt(0)" ::: "memory"); \
  __builtin_amdgcn_s_setprio(1);

#define PH_END(VM)                                                    \
  __builtin_amdgcn_s_setprio(0);                                      \
  if ((VM) == 4) asm volatile("s_waitcnt vmcnt(4)" ::: "memory");     \
  if ((VM) == 0) asm volatile("s_waitcnt vmcnt(0)" ::: "memory");     \
  __builtin_amdgcn_s_barrier();

#define RDA(IB, G)                                                \
  _Pragma("unroll") for (int i2 = 0; i2 < 4; ++i2) {              \
    af[i2 * 2 + 0] = *(const bf16x8*)((G) + ((IB) + i2) * 2048 + a0); \
    af[i2 * 2 + 1] = *(const bf16x8*)((G) + ((IB) + i2) * 2048 + a1); \
  }
#define RDB(JB, G)                                                \
  _Pragma("unroll") for (int j2 = 0; j2 < 2; ++j2) {              \
    bf[(JB) * 2 + j2 * 2 + 0] = *(const bf16x8*)((G) + ((JB) + j2) * 2048 + b0); \
    bf[(JB) * 2 + j2 * 2 + 1] = *(const bf16x8*)((G) + ((JB) + j2) * 2048 + b1); \
  }

#define MMQ(IB, JB)                                                           \
  _Pragma("unroll") for (int i2 = 0; i2 < 4; ++i2)                            \
  _Pragma("unroll") for (int j2 = 0; j2 < 2; ++j2)                            \
  _Pragma("unroll") for (int kk = 0; kk < 2; ++kk)                            \
      acc[(IB) + i2][(JB) + j2] = __builtin_amdgcn_mfma_f32_16x16x32_bf16(    \
          af[i2 * 2 + kk], bf[(JB) * 2 + j2 * 2 + kk], acc[(IB) + i2][(JB) + j2], 0, 0, 0);

  // ---- prologue: stage tile 0 (4 granules), drain, barrier ----
  STAGEG(Abase, 0,   0, ADST(0, 0));
  STAGEG(Abase, 128, 0, ADST(0, 1));
  STAGEG(Bbase, 0,   0, BDST(0, 0));
  STAGEG(Bbase, 128, 0, BDST(0, 1));
  asm volatile("s_waitcnt vmcnt(0)" ::: "memory");
  __builtin_amdgcn_s_barrier();

#define TILE(tt, CUR)                                        \
  {                                                          \
    const int ktn = (((tt) + 1 < NT) ? (tt) + 1 : NT - 1) * 64; \
    /* ph0 */                                                \
    RDA(0, AWG(CUR)); RDB(0, BWG(CUR));                      \
    STAGEG(Abase, 0,   ktn, ADST(CUR ^ 1, 0));               \
    STAGEG(Abase, 128, ktn, ADST(CUR ^ 1, 1));               \
    PH_MID(); MMQ(0, 0); PH_END(9);                          \
    /* ph1 */                                                \
    RDB(2, BWG(CUR));                                        \
    STAGEG(Bbase, 0,   ktn, BDST(CUR ^ 1, 0));               \
    STAGEG(Bbase, 128, ktn, BDST(CUR ^ 1, 1));               \
    PH_MID(); MMQ(0, 2); PH_END(9);                          \
    /* ph2 */                                                \
    RDA(4, AWG(CUR));                                        \
    PH_MID(); MMQ(4, 0); PH_END(4);                          \
    /* ph3 */                                                \
    PH_MID(); MMQ(4, 2); PH_END(0);                          \
  }

#pragma unroll 1
  for (int t2 = 0; t2 < NT; t2 += 2) {
    TILE(t2, 0);
    TILE(t2 + 1, 1);
  }

  asm volatile("s_waitcnt vmcnt(0)" ::: "memory");

  // ---- epilogue: C/D layout col=lane&15, row=(lane>>4)*4+reg ----
  const int crow = (lane >> 4) * 4;
  const int ccol = lane & 15;
#pragma unroll
  for (int i = 0; i < 8; ++i) {
#pragma unroll
    for (int j = 0; j < 4; ++j) {
      const int mrow = m0 + wm * 128 + i * 16 + crow;
      const int ncol = n0 + wn * 64 + j * 16 + ccol;
      const float bv = bias[ncol];
#pragma unroll
      for (int r = 0; r < 4; ++r) {
        float v = acc[i][j][r] + bv;
        if (STORE_BF16)
          ((__bf16*)Cout)[(long)(mrow + r) * N + ncol] = (__bf16)v;
        else
          ((float*)Cout)[(long)(mrow + r) * N + ncol] = v;
      }
    }
  }
#undef TILE
#undef STAGEG
#undef PH_MID
#undef PH_END
#undef RDA
#undef RDB
#undef MMQ
#undef ADST
#undef BDST
#undef AWG
#undef BWG
}

// ------- fused GLU + depthwise conv (K=31, pad 15) + bias + mask -------
// Tap-major transposed LDS: sgT[128 ch][32 quads x4] with XOR quad swizzle.
__global__ __launch_bounds__(256, 2)
void glu_conv_kernel(const __bf16* __restrict__ X, const float* __restrict__ Wsm,
                     const float* __restrict__ bias, const int* __restrict__ mask,
                     __bf16* __restrict__ Y) {
  const int b  = blockIdx.z;
  const int t0 = blockIdx.y * 64;
  const int c0 = blockIdx.x * 128;
  __shared__ float sgT[128][128];
  __shared__ float swl[124];
  const int tid = threadIdx.x;
  if (tid < 124) swl[tid] = Wsm[tid];

  for (int i = tid; i < 2048; i += 256) {
    const int ttl = i & 127;
    const int cg  = i >> 7;
    if (ttl < 94) {
      const int t = t0 - 15 + ttl;
      float v[8];
      if (t >= 0 && t < 1024) {
        const __bf16* p = X + ((long)(b * 1024 + t)) * 2048 + c0 + cg * 8;
        bf16x8 a8 = *(const bf16x8*)p;
        bf16x8 g8 = *(const bf16x8*)(p + 1024);
#pragma unroll
        for (int j = 0; j < 8; ++j) {
          float av = (float)a8[j], gv = (float)g8[j];
          v[j] = av / (1.f + __expf(-gv));
        }
      } else {
#pragma unroll
        for (int j = 0; j < 8; ++j) v[j] = 0.f;
      }
      const int q = ttl >> 2, e = ttl & 3;
#pragma unroll
      for (int j = 0; j < 8; ++j) {
        const int c = cg * 8 + j;
        sgT[c][((q ^ ((c & 7) << 2)) << 2) + e] = v[j];
      }
    }
  }
  __syncthreads();

  const int cc = tid & 127;
  const int th = tid >> 7;
  const int c  = c0 + cc;
  const float* wrow = swl + (c & 3) * 31;
  const float bv = bias[c];
  float acc[32];
#pragma unroll
  for (int u = 0; u < 32; ++u) acc[u] = bv;
  const int key = (cc & 7) << 2;
#pragma unroll
  for (int qi = 0; qi < 16; ++qi) {
    const int q = th * 8 + qi;
    const f32x4 w4 = *(const f32x4*)&sgT[cc][(q ^ key) << 2];
#pragma unroll
    for (int j = 0; j < 4; ++j) {
      const int rl = qi * 4 + j;
#pragma unroll
      for (int u = 0; u < 32; ++u) {
        const int k = rl - u;
        if (k >= 0 && k < 31) acc[u] += w4[j] * wrow[k];
      }
    }
  }
  const long yb = (long)b * 1024 * 1024;
#pragma unroll
  for (int u = 0; u < 32; ++u) {
    const int gt = t0 + th * 32 + u;
    float v = acc[u];
    if (mask[b * 1024 + gt] == 0) v = 0.f;
    Y[yb + (long)gt * 1024 + c] = (__bf16)v;
  }
}

extern "C" void kernel_launch(void* const* d_in, const int* in_sizes, int n_in,
                              void* d_out, int out_size, void* d_ws, size_t ws_size,
                              hipStream_t stream) {
  const float* q    = (const float*)d_in[0];
  const int*   mask = (const int*)d_in[3];
  const float* W1   = (const float*)d_in[4];
  const float* b1   = (const float*)d_in[5];
  const float* W2   = (const float*)d_in[6];
  const float* b2   = (const float*)d_in[7];
  const float* cw   = (const float*)d_in[8];
  const float* bias = (const float*)d_in[9];

  char* ws = (char*)d_ws;
  __bf16* q_bf  = (__bf16*)(ws);                // 32 MB, reused as Y
  __bf16* w1_bf = (__bf16*)(ws + (32u << 20));  // 4 MB
  __bf16* w2_bf = (__bf16*)(ws + (36u << 20));  // 2 MB
  float*  swm   = (float*)(ws + (38u << 20));   // 496 B
  __bf16* x1    = (__bf16*)d_out;  // (B,T,2C) bf16 = 64 MB, freed before GEMM2
  __bf16* y_bf  = q_bf;

  cvt_bf16_kernel<<<2048, 256, 0, stream>>>(q, q_bf, 16 * 1024 * 1024 / 4);
  cvt_bf16_kernel<<<512, 256, 0, stream>>>(W1, w1_bf, 2048 * 1024 / 4);
  cvt_bf16_kernel<<<256, 256, 0, stream>>>(W2, w2_bf, 1024 * 1024 / 4);
  softmax_w_kernel<<<1, 64, 0, stream>>>(cw, swm);

  // GEMM1 + b1 -> x1 (bf16): grid 64x8 = 512 blocks
  gemm256_kernel<1><<<512, 512, 0, stream>>>(q_bf, w1_bf, b1, (void*)x1,
                                             16384, 2048, 1024, 8);
  // GLU + conv + bias + mask -> y (bf16)
  glu_conv_kernel<<<dim3(8, 16, 16), 256, 0, stream>>>(x1, swm, bias, mask, y_bf);
  // GEMM2 + b2 -> d_out (f32): grid 64x4 = 256 blocks
  gemm256_kernel<0><<<256, 512, 0, stream>>>(y_bf, w2_bf, b2, d_out,
                                             16384, 1024, 1024, 4);
}

// Round 5
// 183.567 us; speedup vs baseline: 1.3219x; 1.0137x over previous
//
#include <hip/hip_runtime.h>

typedef __attribute__((ext_vector_type(8))) __bf16 bf16x8;
typedef __attribute__((ext_vector_type(4))) __bf16 bf16x4;
typedef __attribute__((ext_vector_type(4))) float  f32x4;
typedef __attribute__((ext_vector_type(4))) float  float4v;

#define DEV static __device__ __forceinline__

DEV void gload_lds16(const void* g, void* l) {
  __builtin_amdgcn_global_load_lds(
      (const __attribute__((address_space(1))) void*)g,
      (__attribute__((address_space(3))) void*)l, 16, 0, 0);
}

// ---------------- f32 -> bf16 convert (vectorized) ----------------
__global__ void cvt_bf16_kernel(const float* __restrict__ in,
                                __bf16* __restrict__ out, int n4) {
  int stride = gridDim.x * blockDim.x;
  for (int i = blockIdx.x * blockDim.x + threadIdx.x; i < n4; i += stride) {
    float4v v = ((const float4v*)in)[i];
    bf16x4 o;
#pragma unroll
    for (int j = 0; j < 4; ++j) o[j] = (__bf16)v[j];
    ((bf16x4*)out)[i] = o;
  }
}

// ------- W1 convert + GLU interleave permute: w1p[2c]=W1[c], w1p[2c+1]=W1[c+1024]
__global__ void cvt_w1_perm_kernel(const float* __restrict__ W1,
                                   __bf16* __restrict__ out) {
  const int tid = threadIdx.x;
  const int r   = blockIdx.x * 2 + (tid >> 7);   // out row 0..2047
  const int col = (tid & 127) * 8;
  const int src = (r >> 1) + (r & 1) * 1024;
  const float* p = W1 + (long)src * 1024 + col;
  float4v v0 = *(const float4v*)p;
  float4v v1 = *(const float4v*)(p + 4);
  bf16x8 o;
#pragma unroll
  for (int j = 0; j < 4; ++j) { o[j] = (__bf16)v0[j]; o[4 + j] = (__bf16)v1[j]; }
  *(bf16x8*)(out + (long)r * 1024 + col) = o;
}

// ---------- softmax of conv_w (H=4,K=31) + b1 interleave permute ----------
__global__ void prep_kernel(const float* __restrict__ cw, const float* __restrict__ b1,
                            float* __restrict__ swm, float* __restrict__ b1p) {
  const int tid = threadIdx.x;
  if (tid < 4) {
    const int h = tid;
    float m = cw[h * 31];
#pragma unroll
    for (int k = 1; k < 31; ++k) m = fmaxf(m, cw[h * 31 + k]);
    float e[31];
    float s = 0.f;
#pragma unroll
    for (int k = 0; k < 31; ++k) {
      e[k] = __expf(cw[h * 31 + k] - m);
      s += e[k];
    }
    float inv = 1.f / s;
#pragma unroll
    for (int k = 0; k < 31; ++k) swm[h * 31 + k] = e[k] * inv;
  }
  for (int i = tid; i < 2048; i += 256)
    b1p[i] = b1[(i >> 1) + (i & 1) * 1024];
}

// ============ 256x256 8-phase GEMM body (R4 structure) ============
// MODE 0: C = A*Bw^T + bias, f32 store. MODE 1: GLU epilogue — Bw is
// interleave-permuted; out[t][n>>1] = a*sigmoid(g) from lane pairs, bf16.
template <int MODE>
DEV void gemm_body(const __bf16* __restrict__ A, const __bf16* __restrict__ Bw,
                   const float* __restrict__ bias, void* __restrict__ Cout,
                   int M, int N, int K, int ntn) {
  __shared__ __align__(16) __bf16 Al[4 * 8192];
  __shared__ __align__(16) __bf16 Bl[4 * 8192];

  const int tid  = threadIdx.x;
  const int lane = tid & 63;
  const int w    = tid >> 6;
  const int wm = w >> 2, wn = w & 3;

  const int nwg = gridDim.x;
  const int cpx = nwg >> 3;
  const int bid = blockIdx.x;
  const int wgid = (bid & 7) * cpx + (bid >> 3);
  const int m0 = (wgid / ntn) * 256;
  const int n0 = (wgid % ntn) * 256;

  const int NT = K >> 6;

  const int scolE = ((((tid & 7) * 16) ^ (((tid >> 3) & 7) << 4)) >> 1);
  const __bf16* __restrict__ Abase = A + (long)m0 * K;
  const __bf16* __restrict__ Bbase = Bw + (long)n0 * K;

  const int l15 = lane & 15;
  const int xk  = (l15 & 7) << 4;
  const int a0  = l15 * 128 + (((lane >> 4) * 16) ^ xk);
  const int a1  = l15 * 128 + ((((lane >> 4) * 16) + 64) ^ xk);
  const int bq  = (wn & 1) * 8192;
  const int b0  = bq + a0;
  const int b1r = bq + a1;

  f32x4 acc[8][4];
#pragma unroll
  for (int i = 0; i < 8; ++i)
#pragma unroll
    for (int j = 0; j < 4; ++j) {
      acc[i][j][0] = 0.f; acc[i][j][1] = 0.f;
      acc[i][j][2] = 0.f; acc[i][j][3] = 0.f;
    }
  bf16x8 af[8], bf[8];

#define ADST(p, mh) (Al + ((p) * 2 + (mh)) * 8192)
#define BDST(p, nh) (Bl + ((p) * 2 + (nh)) * 8192)
#define AWG(p) ((const char*)Al + ((p) * 2 + wm) * 16384)
#define BWG(p) ((const char*)Bl + ((p) * 2 + (wn >> 1)) * 16384)

#define STAGEG(base, groff, ktc, dst)                                             \
  {                                                                               \
    const __bf16* _s = (base) + (long)((groff) + (tid >> 3)) * K + (ktc) + scolE; \
    gload_lds16(_s, (dst) + tid * 8);                                             \
    gload_lds16(_s + (long)64 * K, (dst) + 4096 + tid * 8);                       \
  }

#define PH_MID()                                     \
  __builtin_amdgcn_s_barrier();                      \
  asm volatile("s_waitcnt lgkmcnt(0)" ::: "memory"); \
  __builtin_amdgcn_s_setprio(1);

#define PH_END(VM)                                                    \
  __builtin_amdgcn_s_setprio(0);                                      \
  if ((VM) == 4) asm volatile("s_waitcnt vmcnt(4)" ::: "memory");     \
  if ((VM) == 0) asm volatile("s_waitcnt vmcnt(0)" ::: "memory");     \
  __builtin_amdgcn_s_barrier();

#define RDA(IB, G)                                                    \
  _Pragma("unroll") for (int i2 = 0; i2 < 4; ++i2) {                  \
    af[i2 * 2 + 0] = *(const bf16x8*)((G) + ((IB) + i2) * 2048 + a0); \
    af[i2 * 2 + 1] = *(const bf16x8*)((G) + ((IB) + i2) * 2048 + a1); \
  }
#define RDB(JB, G)                                                                \
  _Pragma("unroll") for (int j2 = 0; j2 < 2; ++j2) {                              \
    bf[(JB) * 2 + j2 * 2 + 0] = *(const bf16x8*)((G) + ((JB) + j2) * 2048 + b0);  \
    bf[(JB) * 2 + j2 * 2 + 1] = *(const bf16x8*)((G) + ((JB) + j2) * 2048 + b1r); \
  }

#define MMQ(IB, JB)                                                           \
  _Pragma("unroll") for (int i2 = 0; i2 < 4; ++i2)                            \
  _Pragma("unroll") for (int j2 = 0; j2 < 2; ++j2)                            \
  _Pragma("unroll") for (int kk = 0; kk < 2; ++kk)                            \
      acc[(IB) + i2][(JB) + j2] = __builtin_amdgcn_mfma_f32_16x16x32_bf16(    \
          af[i2 * 2 + kk], bf[(JB) * 2 + j2 * 2 + kk], acc[(IB) + i2][(JB) + j2], 0, 0, 0);

  STAGEG(Abase, 0,   0, ADST(0, 0));
  STAGEG(Abase, 128, 0, ADST(0, 1));
  STAGEG(Bbase, 0,   0, BDST(0, 0));
  STAGEG(Bbase, 128, 0, BDST(0, 1));
  asm volatile("s_waitcnt vmcnt(0)" ::: "memory");
  __builtin_amdgcn_s_barrier();

#define TILE(tt, CUR)                                           \
  {                                                             \
    const int ktn = (((tt) + 1 < NT) ? (tt) + 1 : NT - 1) * 64; \
    RDA(0, AWG(CUR)); RDB(0, BWG(CUR));                         \
    STAGEG(Abase, 0,   ktn, ADST(CUR ^ 1, 0));                  \
    STAGEG(Abase, 128, ktn, ADST(CUR ^ 1, 1));                  \
    PH_MID(); MMQ(0, 0); PH_END(9);                             \
    RDB(2, BWG(CUR));                                           \
    STAGEG(Bbase, 0,   ktn, BDST(CUR ^ 1, 0));                  \
    STAGEG(Bbase, 128, ktn, BDST(CUR ^ 1, 1));                  \
    PH_MID(); MMQ(0, 2); PH_END(9);                             \
    RDA(4, AWG(CUR));                                           \
    PH_MID(); MMQ(4, 0); PH_END(4);                             \
    PH_MID(); MMQ(4, 2); PH_END(0);                             \
  }

#pragma unroll 1
  for (int t2 = 0; t2 < NT; t2 += 2) {
    TILE(t2, 0);
    TILE(t2 + 1, 1);
  }

  asm volatile("s_waitcnt vmcnt(0)" ::: "memory");

  // ---- epilogue: C/D layout col=lane&15, row=(lane>>4)*4+reg ----
  const int crow = (lane >> 4) * 4;
  const int ccol = lane & 15;
#pragma unroll
  for (int i = 0; i < 8; ++i) {
#pragma unroll
    for (int j = 0; j < 4; ++j) {
      const int mrow = m0 + wm * 128 + i * 16 + crow;
      const int ncol = n0 + wn * 64 + j * 16 + ccol;
      const float bv = bias[ncol];
#pragma unroll
      for (int r = 0; r < 4; ++r) {
        float v = acc[i][j][r] + bv;
        if (MODE == 0) {
          ((float*)Cout)[(long)(mrow + r) * N + ncol] = v;
        } else {
          // GLU: even lane holds a, odd lane holds g (interleaved W1)
          float o = __shfl_xor(v, 1);
          if (!(lane & 1)) {
            float res = v / (1.f + __expf(-o));
            ((__bf16*)Cout)[(long)(mrow + r) * (N >> 1) + (ncol >> 1)] = (__bf16)res;
          }
        }
      }
    }
  }
#undef TILE
#undef STAGEG
#undef PH_MID
#undef PH_END
#undef RDA
#undef RDB
#undef MMQ
#undef ADST
#undef BDST
#undef AWG
#undef BWG
}

__global__ __launch_bounds__(512, 2)
void gemm1_glu_kernel(const __bf16* __restrict__ A, const __bf16* __restrict__ Bw,
                      const float* __restrict__ bias, void* __restrict__ Cout,
                      int M, int N, int K, int ntn) {
  gemm_body<1>(A, Bw, bias, Cout, M, N, K, ntn);
}

__global__ __launch_bounds__(512, 2)
void gemm2_out_kernel(const __bf16* __restrict__ A, const __bf16* __restrict__ Bw,
                      const float* __restrict__ bias, void* __restrict__ Cout,
                      int M, int N, int K, int ntn) {
  gemm_body<0>(A, Bw, bias, Cout, M, N, K, ntn);
}

// ------- depthwise conv (K=31, pad 15) + bias + mask (input already GLU'd) ----
// Tap-major transposed LDS: sgT[128 ch][32 quads x4] with XOR quad swizzle.
__global__ __launch_bounds__(256, 2)
void conv_kernel(const __bf16* __restrict__ Yin, const float* __restrict__ Wsm,
                 const float* __restrict__ bias, const int* __restrict__ mask,
                 __bf16* __restrict__ Y) {
  const int b  = blockIdx.z;
  const int t0 = blockIdx.y * 64;
  const int c0 = blockIdx.x * 128;
  __shared__ float sgT[128][128];
  __shared__ float swl[124];
  const int tid = threadIdx.x;
  if (tid < 124) swl[tid] = Wsm[tid];

  for (int i = tid; i < 2048; i += 256) {
    const int ttl = i & 127;  // tap 0..127 (94 used)
    const int cg  = i >> 7;   // channel octet 0..15
    if (ttl < 94) {
      const int t = t0 - 15 + ttl;
      float v[8];
      if (t >= 0 && t < 1024) {
        bf16x8 a8 = *(const bf16x8*)(Yin + ((long)(b * 1024 + t)) * 1024 + c0 + cg * 8);
#pragma unroll
        for (int j = 0; j < 8; ++j) v[j] = (float)a8[j];
      } else {
#pragma unroll
        for (int j = 0; j < 8; ++j) v[j] = 0.f;
      }
      const int q = ttl >> 2, e = ttl & 3;
#pragma unroll
      for (int j = 0; j < 8; ++j) {
        const int c = cg * 8 + j;
        sgT[c][((q ^ ((c & 7) << 2)) << 2) + e] = v[j];
      }
    }
  }
  __syncthreads();

  const int cc = tid & 127;
  const int th = tid >> 7;
  const int c  = c0 + cc;
  const float* wrow = swl + (c & 3) * 31;
  const float bv = bias[c];
  float acc[32];
#pragma unroll
  for (int u = 0; u < 32; ++u) acc[u] = bv;
  const int key = (cc & 7) << 2;
#pragma unroll
  for (int qi = 0; qi < 16; ++qi) {
    const int q = th * 8 + qi;
    const f32x4 w4 = *(const f32x4*)&sgT[cc][(q ^ key) << 2];
#pragma unroll
    for (int j = 0; j < 4; ++j) {
      const int rl = qi * 4 + j;
#pragma unroll
      for (int u = 0; u < 32; ++u) {
        const int k = rl - u;
        if (k >= 0 && k < 31) acc[u] += w4[j] * wrow[k];
      }
    }
  }
  const long yb = (long)b * 1024 * 1024;
#pragma unroll
  for (int u = 0; u < 32; ++u) {
    const int gt = t0 + th * 32 + u;
    float v = acc[u];
    if (mask[b * 1024 + gt] == 0) v = 0.f;
    Y[yb + (long)gt * 1024 + c] = (__bf16)v;
  }
}

extern "C" void kernel_launch(void* const* d_in, const int* in_sizes, int n_in,
                              void* d_out, int out_size, void* d_ws, size_t ws_size,
                              hipStream_t stream) {
  const float* q    = (const float*)d_in[0];
  const int*   mask = (const int*)d_in[3];
  const float* W1   = (const float*)d_in[4];
  const float* b1   = (const float*)d_in[5];
  const float* W2   = (const float*)d_in[6];
  const float* b2   = (const float*)d_in[7];
  const float* cw   = (const float*)d_in[8];
  const float* bias = (const float*)d_in[9];

  char* ws = (char*)d_ws;
  __bf16* q_bf  = (__bf16*)(ws);                // 32 MB; dead after GEMM1 -> reused as yc
  __bf16* w1p   = (__bf16*)(ws + (32u << 20));  // 4 MB (permuted)
  __bf16* w2_bf = (__bf16*)(ws + (36u << 20));  // 2 MB
  float*  swm   = (float*)(ws + (38u << 20));   // 496 B
  float*  b1p   = (float*)(ws + (38u << 20) + 4096);  // 8 KB (permuted)
  __bf16* y     = (__bf16*)d_out;               // (B,T,C) bf16 = 32 MB; dead after conv
  __bf16* yc    = q_bf;                         // conv output over dead q_bf

  cvt_bf16_kernel<<<2048, 256, 0, stream>>>(q, q_bf, 16 * 1024 * 1024 / 4);
  cvt_w1_perm_kernel<<<1024, 256, 0, stream>>>(W1, w1p);
  cvt_bf16_kernel<<<256, 256, 0, stream>>>(W2, w2_bf, 1024 * 1024 / 4);
  prep_kernel<<<1, 256, 0, stream>>>(cw, b1, swm, b1p);

  // GEMM1 (+b1, GLU fused) -> y bf16 (B,T,C) in d_out. grid 64x8=512.
  gemm1_glu_kernel<<<512, 512, 0, stream>>>(q_bf, w1p, b1p, (void*)y,
                                            16384, 2048, 1024, 8);
  // depthwise conv + bias + mask: y -> yc
  conv_kernel<<<dim3(8, 16, 16), 256, 0, stream>>>(y, swm, bias, mask, yc);
  // GEMM2 + b2 -> d_out f32. grid 64x4=256.
  gemm2_out_kernel<<<256, 512, 0, stream>>>(yc, w2_bf, b2, d_out,
                                            16384, 1024, 1024, 4);
}

// Round 6
// 168.437 us; speedup vs baseline: 1.4406x; 1.0898x over previous
//
#include <hip/hip_runtime.h>

typedef __attribute__((ext_vector_type(8))) __bf16 bf16x8;
typedef __attribute__((ext_vector_type(4))) __bf16 bf16x4;
typedef __attribute__((ext_vector_type(4))) float  f32x4;
typedef __attribute__((ext_vector_type(4))) float  float4v;

#define DEV static __device__ __forceinline__

DEV void gload_lds16(const void* g, void* l) {
  __builtin_amdgcn_global_load_lds(
      (const __attribute__((address_space(1))) void*)g,
      (__attribute__((address_space(3))) void*)l, 16, 0, 0);
}

// ---------------- f32 -> bf16 convert (vectorized) ----------------
__global__ void cvt_bf16_kernel(const float* __restrict__ in,
                                __bf16* __restrict__ out, int n4) {
  int stride = gridDim.x * blockDim.x;
  for (int i = blockIdx.x * blockDim.x + threadIdx.x; i < n4; i += stride) {
    float4v v = ((const float4v*)in)[i];
    bf16x4 o;
#pragma unroll
    for (int j = 0; j < 4; ++j) o[j] = (__bf16)v[j];
    ((bf16x4*)out)[i] = o;
  }
}

// W1 convert + same-lane GLU permute.
// Out row n: g=n>>8, p=n&255, wn=p>>6, jj=(p>>4)&3, c16=p&15;
// ch = g*128 + wn*32 + (jj&1)*16 + c16; src = ch + (jj>=2)*1024.
__global__ void cvt_w1_perm_kernel(const float* __restrict__ W1,
                                   __bf16* __restrict__ out) {
  const int tid = threadIdx.x;
  const int r   = blockIdx.x * 2 + (tid >> 7);   // out row 0..2047
  const int col = (tid & 127) * 8;
  const int g  = r >> 8, p = r & 255;
  const int wn = p >> 6, jj = (p >> 4) & 3, c16 = p & 15;
  const int ch = g * 128 + wn * 32 + (jj & 1) * 16 + c16;
  const int src = ch + (jj >= 2 ? 1024 : 0);
  const float* ptr = W1 + (long)src * 1024 + col;
  float4v v0 = *(const float4v*)ptr;
  float4v v1 = *(const float4v*)(ptr + 4);
  bf16x8 o;
#pragma unroll
  for (int j = 0; j < 4; ++j) { o[j] = (__bf16)v0[j]; o[4 + j] = (__bf16)v1[j]; }
  *(bf16x8*)(out + (long)r * 1024 + col) = o;
}

// ---------- softmax of conv_w (H=4,K=31) + b1 same permute ----------
__global__ void prep_kernel(const float* __restrict__ cw, const float* __restrict__ b1,
                            float* __restrict__ swm, float* __restrict__ b1p) {
  const int tid = threadIdx.x;
  if (tid < 4) {
    const int h = tid;
    float m = cw[h * 31];
#pragma unroll
    for (int k = 1; k < 31; ++k) m = fmaxf(m, cw[h * 31 + k]);
    float e[31];
    float s = 0.f;
#pragma unroll
    for (int k = 0; k < 31; ++k) {
      e[k] = __expf(cw[h * 31 + k] - m);
      s += e[k];
    }
    float inv = 1.f / s;
#pragma unroll
    for (int k = 0; k < 31; ++k) swm[h * 31 + k] = e[k] * inv;
  }
  for (int i = tid; i < 2048; i += 256) {
    const int g = i >> 8, p = i & 255;
    const int wn = p >> 6, jj = (p >> 4) & 3, c16 = p & 15;
    const int ch = g * 128 + wn * 32 + (jj & 1) * 16 + c16;
    b1p[i] = b1[ch + (jj >= 2 ? 1024 : 0)];
  }
}

// ============ 256x256 8-phase GEMM body (R4 structure) ============
// MODE 0: C = A*Bw^T + bias, f32 store.
// MODE 1: GLU epilogue — Bw/bias are same-lane permuted; channel a in
// acc[i][j][.], gate g in acc[i][j+2][.] (j=0,1); out bf16 (M x N/2).
template <int MODE>
DEV void gemm_body(const __bf16* __restrict__ A, const __bf16* __restrict__ Bw,
                   const float* __restrict__ bias, void* __restrict__ Cout,
                   int M, int N, int K, int ntn) {
  __shared__ __align__(16) __bf16 Al[4 * 8192];
  __shared__ __align__(16) __bf16 Bl[4 * 8192];

  const int tid  = threadIdx.x;
  const int lane = tid & 63;
  const int w    = tid >> 6;
  const int wm = w >> 2, wn = w & 3;

  const int nwg = gridDim.x;
  const int cpx = nwg >> 3;
  const int bid = blockIdx.x;
  const int wgid = (bid & 7) * cpx + (bid >> 3);
  const int m0 = (wgid / ntn) * 256;
  const int n0 = (wgid % ntn) * 256;

  const int NT = K >> 6;

  const int scolE = ((((tid & 7) * 16) ^ (((tid >> 3) & 7) << 4)) >> 1);
  const __bf16* __restrict__ Abase = A + (long)m0 * K;
  const __bf16* __restrict__ Bbase = Bw + (long)n0 * K;

  const int l15 = lane & 15;
  const int xk  = (l15 & 7) << 4;
  const int a0  = l15 * 128 + (((lane >> 4) * 16) ^ xk);
  const int a1  = l15 * 128 + ((((lane >> 4) * 16) + 64) ^ xk);
  const int bq  = (wn & 1) * 8192;
  const int b0  = bq + a0;
  const int b1r = bq + a1;

  f32x4 acc[8][4];
#pragma unroll
  for (int i = 0; i < 8; ++i)
#pragma unroll
    for (int j = 0; j < 4; ++j) {
      acc[i][j][0] = 0.f; acc[i][j][1] = 0.f;
      acc[i][j][2] = 0.f; acc[i][j][3] = 0.f;
    }
  bf16x8 af[8], bf[8];

#define ADST(p, mh) (Al + ((p) * 2 + (mh)) * 8192)
#define BDST(p, nh) (Bl + ((p) * 2 + (nh)) * 8192)
#define AWG(p) ((const char*)Al + ((p) * 2 + wm) * 16384)
#define BWG(p) ((const char*)Bl + ((p) * 2 + (wn >> 1)) * 16384)

#define STAGEG(base, groff, ktc, dst)                                             \
  {                                                                               \
    const __bf16* _s = (base) + (long)((groff) + (tid >> 3)) * K + (ktc) + scolE; \
    gload_lds16(_s, (dst) + tid * 8);                                             \
    gload_lds16(_s + (long)64 * K, (dst) + 4096 + tid * 8);                       \
  }

#define PH_MID()                                     \
  __builtin_amdgcn_s_barrier();                      \
  asm volatile("s_waitcnt lgkmcnt(0)" ::: "memory"); \
  __builtin_amdgcn_s_setprio(1);

#define PH_END(VM)                                                    \
  __builtin_amdgcn_s_setprio(0);                                      \
  if ((VM) == 4) asm volatile("s_waitcnt vmcnt(4)" ::: "memory");     \
  if ((VM) == 0) asm volatile("s_waitcnt vmcnt(0)" ::: "memory");     \
  __builtin_amdgcn_s_barrier();

#define RDA(IB, G)                                                    \
  _Pragma("unroll") for (int i2 = 0; i2 < 4; ++i2) {                  \
    af[i2 * 2 + 0] = *(const bf16x8*)((G) + ((IB) + i2) * 2048 + a0); \
    af[i2 * 2 + 1] = *(const bf16x8*)((G) + ((IB) + i2) * 2048 + a1); \
  }
#define RDB(JB, G)                                                                \
  _Pragma("unroll") for (int j2 = 0; j2 < 2; ++j2) {                              \
    bf[(JB) * 2 + j2 * 2 + 0] = *(const bf16x8*)((G) + ((JB) + j2) * 2048 + b0);  \
    bf[(JB) * 2 + j2 * 2 + 1] = *(const bf16x8*)((G) + ((JB) + j2) * 2048 + b1r); \
  }

#define MMQ(IB, JB)                                                           \
  _Pragma("unroll") for (int i2 = 0; i2 < 4; ++i2)                            \
  _Pragma("unroll") for (int j2 = 0; j2 < 2; ++j2)                            \
  _Pragma("unroll") for (int kk = 0; kk < 2; ++kk)                            \
      acc[(IB) + i2][(JB) + j2] = __builtin_amdgcn_mfma_f32_16x16x32_bf16(    \
          af[i2 * 2 + kk], bf[(JB) * 2 + j2 * 2 + kk], acc[(IB) + i2][(JB) + j2], 0, 0, 0);

  STAGEG(Abase, 0,   0, ADST(0, 0));
  STAGEG(Abase, 128, 0, ADST(0, 1));
  STAGEG(Bbase, 0,   0, BDST(0, 0));
  STAGEG(Bbase, 128, 0, BDST(0, 1));
  asm volatile("s_waitcnt vmcnt(0)" ::: "memory");
  __builtin_amdgcn_s_barrier();

#define TILE(tt, CUR)                                           \
  {                                                             \
    const int ktn = (((tt) + 1 < NT) ? (tt) + 1 : NT - 1) * 64; \
    RDA(0, AWG(CUR)); RDB(0, BWG(CUR));                         \
    STAGEG(Abase, 0,   ktn, ADST(CUR ^ 1, 0));                  \
    STAGEG(Abase, 128, ktn, ADST(CUR ^ 1, 1));                  \
    PH_MID(); MMQ(0, 0); PH_END(9);                             \
    RDB(2, BWG(CUR));                                           \
    STAGEG(Bbase, 0,   ktn, BDST(CUR ^ 1, 0));                  \
    STAGEG(Bbase, 128, ktn, BDST(CUR ^ 1, 1));                  \
    PH_MID(); MMQ(0, 2); PH_END(9);                             \
    RDA(4, AWG(CUR));                                           \
    PH_MID(); MMQ(4, 0); PH_END(4);                             \
    PH_MID(); MMQ(4, 2); PH_END(0);                             \
  }

#pragma unroll 1
  for (int t2 = 0; t2 < NT; t2 += 2) {
    TILE(t2, 0);
    TILE(t2 + 1, 1);
  }

  asm volatile("s_waitcnt vmcnt(0)" ::: "memory");

  // ---- epilogue: C/D layout col=lane&15, row=(lane>>4)*4+reg ----
  const int crow = (lane >> 4) * 4;
  const int ccol = lane & 15;
#pragma unroll
  for (int i = 0; i < 8; ++i) {
    const int mrow = m0 + wm * 128 + i * 16 + crow;
    if (MODE == 0) {
#pragma unroll
      for (int j = 0; j < 4; ++j) {
        const int ncol = n0 + wn * 64 + j * 16 + ccol;
        const float bv = bias[ncol];
#pragma unroll
        for (int r = 0; r < 4; ++r)
          ((float*)Cout)[(long)(mrow + r) * N + ncol] = acc[i][j][r] + bv;
      }
    } else {
      // GLU same-lane: a = acc[i][j], g = acc[i][j+2], j = 0,1.
#pragma unroll
      for (int j = 0; j < 2; ++j) {
        const int na = n0 + wn * 64 + j * 16 + ccol;       // permuted index of a
        const float bva = bias[na];
        const float bvg = bias[na + 32];
        const int ch = (n0 >> 1) + wn * 32 + j * 16 + ccol; // true channel
#pragma unroll
        for (int r = 0; r < 4; ++r) {
          float a = acc[i][j][r] + bva;
          float gv = acc[i][j + 2][r] + bvg;
          float res = a / (1.f + __expf(-gv));
          ((__bf16*)Cout)[(long)(mrow + r) * (N >> 1) + ch] = (__bf16)res;
        }
      }
    }
  }
#undef TILE
#undef STAGEG
#undef PH_MID
#undef PH_END
#undef RDA
#undef RDB
#undef MMQ
#undef ADST
#undef BDST
#undef AWG
#undef BWG
}

__global__ __launch_bounds__(512, 2)
void gemm1_glu_kernel(const __bf16* __restrict__ A, const __bf16* __restrict__ Bw,
                      const float* __restrict__ bias, void* __restrict__ Cout,
                      int M, int N, int K, int ntn) {
  gemm_body<1>(A, Bw, bias, Cout, M, N, K, ntn);
}

__global__ __launch_bounds__(512, 2)
void gemm2_out_kernel(const __bf16* __restrict__ A, const __bf16* __restrict__ Bw,
                      const float* __restrict__ bias, void* __restrict__ Cout,
                      int M, int N, int K, int ntn) {
  gemm_body<0>(A, Bw, bias, Cout, M, N, K, ntn);
}

// ------- depthwise conv (K=31, pad 15) + bias + mask (input already GLU'd) ----
__global__ __launch_bounds__(256, 2)
void conv_kernel(const __bf16* __restrict__ Yin, const float* __restrict__ Wsm,
                 const float* __restrict__ bias, const int* __restrict__ mask,
                 __bf16* __restrict__ Y) {
  const int b  = blockIdx.z;
  const int t0 = blockIdx.y * 64;
  const int c0 = blockIdx.x * 128;
  __shared__ float sgT[128][128];
  __shared__ float swl[124];
  const int tid = threadIdx.x;
  if (tid < 124) swl[tid] = Wsm[tid];

  for (int i = tid; i < 2048; i += 256) {
    const int ttl = i & 127;  // tap 0..127 (94 used)
    const int cg  = i >> 7;   // channel octet 0..15
    if (ttl < 94) {
      const int t = t0 - 15 + ttl;
      float v[8];
      if (t >= 0 && t < 1024) {
        bf16x8 a8 = *(const bf16x8*)(Yin + ((long)(b * 1024 + t)) * 1024 + c0 + cg * 8);
#pragma unroll
        for (int j = 0; j < 8; ++j) v[j] = (float)a8[j];
      } else {
#pragma unroll
        for (int j = 0; j < 8; ++j) v[j] = 0.f;
      }
      const int q = ttl >> 2, e = ttl & 3;
#pragma unroll
      for (int j = 0; j < 8; ++j) {
        const int c = cg * 8 + j;
        sgT[c][((q ^ ((c & 7) << 2)) << 2) + e] = v[j];
      }
    }
  }
  __syncthreads();

  const int cc = tid & 127;
  const int th = tid >> 7;
  const int c  = c0 + cc;
  const float* wrow = swl + (c & 3) * 31;
  const float bv = bias[c];
  float acc[32];
#pragma unroll
  for (int u = 0; u < 32; ++u) acc[u] = bv;
  const int key = (cc & 7) << 2;
#pragma unroll
  for (int qi = 0; qi < 16; ++qi) {
    const int q = th * 8 + qi;
    const f32x4 w4 = *(const f32x4*)&sgT[cc][(q ^ key) << 2];
#pragma unroll
    for (int j = 0; j < 4; ++j) {
      const int rl = qi * 4 + j;
#pragma unroll
      for (int u = 0; u < 32; ++u) {
        const int k = rl - u;
        if (k >= 0 && k < 31) acc[u] += w4[j] * wrow[k];
      }
    }
  }
  const long yb = (long)b * 1024 * 1024;
#pragma unroll
  for (int u = 0; u < 32; ++u) {
    const int gt = t0 + th * 32 + u;
    float v = acc[u];
    if (mask[b * 1024 + gt] == 0) v = 0.f;
    Y[yb + (long)gt * 1024 + c] = (__bf16)v;
  }
}

extern "C" void kernel_launch(void* const* d_in, const int* in_sizes, int n_in,
                              void* d_out, int out_size, void* d_ws, size_t ws_size,
                              hipStream_t stream) {
  const float* q    = (const float*)d_in[0];
  const int*   mask = (const int*)d_in[3];
  const float* W1   = (const float*)d_in[4];
  const float* b1   = (const float*)d_in[5];
  const float* W2   = (const float*)d_in[6];
  const float* b2   = (const float*)d_in[7];
  const float* cw   = (const float*)d_in[8];
  const float* bias = (const float*)d_in[9];

  char* ws = (char*)d_ws;
  __bf16* q_bf  = (__bf16*)(ws);                // 32 MB; dead after GEMM1 -> reused as yc
  __bf16* w1p   = (__bf16*)(ws + (32u << 20));  // 4 MB (permuted)
  __bf16* w2_bf = (__bf16*)(ws + (36u << 20));  // 2 MB
  float*  swm   = (float*)(ws + (38u << 20));   // 496 B
  float*  b1p   = (float*)(ws + (38u << 20) + 4096);  // 8 KB (permuted)
  __bf16* y     = (__bf16*)d_out;               // (B,T,C) bf16 = 32 MB; dead after conv
  __bf16* yc    = q_bf;                         // conv output over dead q_bf

  cvt_bf16_kernel<<<2048, 256, 0, stream>>>(q, q_bf, 16 * 1024 * 1024 / 4);
  cvt_w1_perm_kernel<<<1024, 256, 0, stream>>>(W1, w1p);
  cvt_bf16_kernel<<<256, 256, 0, stream>>>(W2, w2_bf, 1024 * 1024 / 4);
  prep_kernel<<<1, 256, 0, stream>>>(cw, b1, swm, b1p);

  // GEMM1 (+b1, GLU fused) -> y bf16 (B,T,C) in d_out. grid 64x8=512.
  gemm1_glu_kernel<<<512, 512, 0, stream>>>(q_bf, w1p, b1p, (void*)y,
                                            16384, 2048, 1024, 8);
  // depthwise conv + bias + mask: y -> yc
  conv_kernel<<<dim3(8, 16, 16), 256, 0, stream>>>(y, swm, bias, mask, yc);
  // GEMM2 + b2 -> d_out f32. grid 64x4=256.
  gemm2_out_kernel<<<256, 512, 0, stream>>>(yc, w2_bf, b2, d_out,
                                            16384, 1024, 1024, 4);
}

// Round 7
// 163.144 us; speedup vs baseline: 1.4874x; 1.0324x over previous
//
#include <hip/hip_runtime.h>

typedef __attribute__((ext_vector_type(8))) __bf16 bf16x8;
typedef __attribute__((ext_vector_type(4))) __bf16 bf16x4;
typedef __attribute__((ext_vector_type(4))) float  f32x4;
typedef __attribute__((ext_vector_type(4))) float  float4v;

#define DEV static __device__ __forceinline__

DEV void gload_lds16(const void* g, void* l) {
  __builtin_amdgcn_global_load_lds(
      (const __attribute__((address_space(1))) void*)g,
      (__attribute__((address_space(3))) void*)l, 16, 0, 0);
}

// ---------------- f32 -> bf16 convert (vectorized) ----------------
__global__ void cvt_bf16_kernel(const float* __restrict__ in,
                                __bf16* __restrict__ out, int n4) {
  int stride = gridDim.x * blockDim.x;
  for (int i = blockIdx.x * blockDim.x + threadIdx.x; i < n4; i += stride) {
    float4v v = ((const float4v*)in)[i];
    bf16x4 o;
#pragma unroll
    for (int j = 0; j < 4; ++j) o[j] = (__bf16)v[j];
    ((bf16x4*)out)[i] = o;
  }
}

// -------- merged prep: W1 perm-cvt | W2 cvt | softmax(conv_w) + b1 perm --------
// blocks 0..1023: W1 same-lane GLU permute (2 rows each).
// blocks 1024..1279: W2 f32->bf16.
// block 1280: softmax + b1p.
__global__ void prep_all_kernel(const float* __restrict__ W1, const float* __restrict__ W2,
                                const float* __restrict__ cw, const float* __restrict__ b1,
                                __bf16* __restrict__ w1p, __bf16* __restrict__ w2b,
                                float* __restrict__ swm, float* __restrict__ b1p) {
  const int blk = blockIdx.x;
  const int tid = threadIdx.x;
  if (blk < 1024) {
    // out row n: g=n>>8, p=n&255, wn=p>>6, jj=(p>>4)&3, c16=p&15;
    // ch = g*128 + wn*32 + (jj&1)*16 + c16; src = ch + (jj>=2)*1024.
    const int r   = blk * 2 + (tid >> 7);
    const int col = (tid & 127) * 8;
    const int g  = r >> 8, p = r & 255;
    const int wn = p >> 6, jj = (p >> 4) & 3, c16 = p & 15;
    const int ch = g * 128 + wn * 32 + (jj & 1) * 16 + c16;
    const int src = ch + (jj >= 2 ? 1024 : 0);
    const float* ptr = W1 + (long)src * 1024 + col;
    float4v v0 = *(const float4v*)ptr;
    float4v v1 = *(const float4v*)(ptr + 4);
    bf16x8 o;
#pragma unroll
    for (int j = 0; j < 4; ++j) { o[j] = (__bf16)v0[j]; o[4 + j] = (__bf16)v1[j]; }
    *(bf16x8*)(w1p + (long)r * 1024 + col) = o;
  } else if (blk < 1280) {
    int i = (blk - 1024) * 256 + tid;  // 0..65535, total 262144 float4s
#pragma unroll 4
    for (; i < 262144; i += 65536) {
      float4v v = ((const float4v*)W2)[i];
      bf16x4 o;
#pragma unroll
      for (int j = 0; j < 4; ++j) o[j] = (__bf16)v[j];
      ((bf16x4*)w2b)[i] = o;
    }
  } else {
    if (tid < 4) {
      const int h = tid;
      float m = cw[h * 31];
#pragma unroll
      for (int k = 1; k < 31; ++k) m = fmaxf(m, cw[h * 31 + k]);
      float e[31];
      float s = 0.f;
#pragma unroll
      for (int k = 0; k < 31; ++k) {
        e[k] = __expf(cw[h * 31 + k] - m);
        s += e[k];
      }
      float inv = 1.f / s;
#pragma unroll
      for (int k = 0; k < 31; ++k) swm[h * 31 + k] = e[k] * inv;
    }
    for (int i = tid; i < 2048; i += 256) {
      const int g = i >> 8, p = i & 255;
      const int wn = p >> 6, jj = (p >> 4) & 3, c16 = p & 15;
      const int ch = g * 128 + wn * 32 + (jj & 1) * 16 + c16;
      b1p[i] = b1[ch + (jj >= 2 ? 1024 : 0)];
    }
  }
}

// ============ 256x256 8-phase GEMM body (R4 structure) ============
// MODE 0: C = A*Bw^T + bias, f32 store.
// MODE 1: GLU epilogue — Bw/bias same-lane permuted; a in acc[i][j],
// g in acc[i][j+2] (j=0,1); rcp-sigmoid; LDS-transposed bf16x8 stores.
template <int MODE>
DEV void gemm_body(const __bf16* __restrict__ A, const __bf16* __restrict__ Bw,
                   const float* __restrict__ bias, void* __restrict__ Cout,
                   int M, int N, int K, int ntn) {
  __shared__ __align__(16) __bf16 Al[4 * 8192];
  __shared__ __align__(16) __bf16 Bl[4 * 8192];

  const int tid  = threadIdx.x;
  const int lane = tid & 63;
  const int w    = tid >> 6;
  const int wm = w >> 2, wn = w & 3;

  const int nwg = gridDim.x;
  const int cpx = nwg >> 3;
  const int bid = blockIdx.x;
  const int wgid = (bid & 7) * cpx + (bid >> 3);
  const int m0 = (wgid / ntn) * 256;
  const int n0 = (wgid % ntn) * 256;

  const int NT = K >> 6;

  const int scolE = ((((tid & 7) * 16) ^ (((tid >> 3) & 7) << 4)) >> 1);
  const __bf16* __restrict__ Abase = A + (long)m0 * K;
  const __bf16* __restrict__ Bbase = Bw + (long)n0 * K;

  const int l15 = lane & 15;
  const int xk  = (l15 & 7) << 4;
  const int a0  = l15 * 128 + (((lane >> 4) * 16) ^ xk);
  const int a1  = l15 * 128 + ((((lane >> 4) * 16) + 64) ^ xk);
  const int bq  = (wn & 1) * 8192;
  const int b0  = bq + a0;
  const int b1r = bq + a1;

  f32x4 acc[8][4];
#pragma unroll
  for (int i = 0; i < 8; ++i)
#pragma unroll
    for (int j = 0; j < 4; ++j) {
      acc[i][j][0] = 0.f; acc[i][j][1] = 0.f;
      acc[i][j][2] = 0.f; acc[i][j][3] = 0.f;
    }
  bf16x8 af[8], bf[8];

#define ADST(p, mh) (Al + ((p) * 2 + (mh)) * 8192)
#define BDST(p, nh) (Bl + ((p) * 2 + (nh)) * 8192)
#define AWG(p) ((const char*)Al + ((p) * 2 + wm) * 16384)
#define BWG(p) ((const char*)Bl + ((p) * 2 + (wn >> 1)) * 16384)

#define STAGEG(base, groff, ktc, dst)                                             \
  {                                                                               \
    const __bf16* _s = (base) + (long)((groff) + (tid >> 3)) * K + (ktc) + scolE; \
    gload_lds16(_s, (dst) + tid * 8);                                             \
    gload_lds16(_s + (long)64 * K, (dst) + 4096 + tid * 8);                       \
  }

#define PH_MID()                                     \
  __builtin_amdgcn_s_barrier();                      \
  asm volatile("s_waitcnt lgkmcnt(0)" ::: "memory"); \
  __builtin_amdgcn_s_setprio(1);

#define PH_END(VM)                                                    \
  __builtin_amdgcn_s_setprio(0);                                      \
  if ((VM) == 4) asm volatile("s_waitcnt vmcnt(4)" ::: "memory");     \
  if ((VM) == 0) asm volatile("s_waitcnt vmcnt(0)" ::: "memory");     \
  __builtin_amdgcn_s_barrier();

#define RDA(IB, G)                                                    \
  _Pragma("unroll") for (int i2 = 0; i2 < 4; ++i2) {                  \
    af[i2 * 2 + 0] = *(const bf16x8*)((G) + ((IB) + i2) * 2048 + a0); \
    af[i2 * 2 + 1] = *(const bf16x8*)((G) + ((IB) + i2) * 2048 + a1); \
  }
#define RDB(JB, G)                                                                \
  _Pragma("unroll") for (int j2 = 0; j2 < 2; ++j2) {                              \
    bf[(JB) * 2 + j2 * 2 + 0] = *(const bf16x8*)((G) + ((JB) + j2) * 2048 + b0);  \
    bf[(JB) * 2 + j2 * 2 + 1] = *(const bf16x8*)((G) + ((JB) + j2) * 2048 + b1r); \
  }

#define MMQ(IB, JB)                                                           \
  _Pragma("unroll") for (int i2 = 0; i2 < 4; ++i2)                            \
  _Pragma("unroll") for (int j2 = 0; j2 < 2; ++j2)                            \
  _Pragma("unroll") for (int kk = 0; kk < 2; ++kk)                            \
      acc[(IB) + i2][(JB) + j2] = __builtin_amdgcn_mfma_f32_16x16x32_bf16(    \
          af[i2 * 2 + kk], bf[(JB) * 2 + j2 * 2 + kk], acc[(IB) + i2][(JB) + j2], 0, 0, 0);

  STAGEG(Abase, 0,   0, ADST(0, 0));
  STAGEG(Abase, 128, 0, ADST(0, 1));
  STAGEG(Bbase, 0,   0, BDST(0, 0));
  STAGEG(Bbase, 128, 0, BDST(0, 1));
  asm volatile("s_waitcnt vmcnt(0)" ::: "memory");
  __builtin_amdgcn_s_barrier();

#define TILE(tt, CUR)                                           \
  {                                                             \
    const int ktn = (((tt) + 1 < NT) ? (tt) + 1 : NT - 1) * 64; \
    RDA(0, AWG(CUR)); RDB(0, BWG(CUR));                         \
    STAGEG(Abase, 0,   ktn, ADST(CUR ^ 1, 0));                  \
    STAGEG(Abase, 128, ktn, ADST(CUR ^ 1, 1));                  \
    PH_MID(); MMQ(0, 0); PH_END(9);                             \
    RDB(2, BWG(CUR));                                           \
    STAGEG(Bbase, 0,   ktn, BDST(CUR ^ 1, 0));                  \
    STAGEG(Bbase, 128, ktn, BDST(CUR ^ 1, 1));                  \
    PH_MID(); MMQ(0, 2); PH_END(9);                             \
    RDA(4, AWG(CUR));                                           \
    PH_MID(); MMQ(4, 0); PH_END(4);                             \
    PH_MID(); MMQ(4, 2); PH_END(0);                             \
  }

#pragma unroll 1
  for (int t2 = 0; t2 < NT; t2 += 2) {
    TILE(t2, 0);
    TILE(t2 + 1, 1);
  }

  asm volatile("s_waitcnt vmcnt(0)" ::: "memory");

  // ---- epilogue: C/D layout col=lane&15, row=(lane>>4)*4+reg ----
  const int crow = (lane >> 4) * 4;
  const int ccol = lane & 15;
  if (MODE == 0) {
#pragma unroll
    for (int i = 0; i < 8; ++i) {
      const int mrow = m0 + wm * 128 + i * 16 + crow;
#pragma unroll
      for (int j = 0; j < 4; ++j) {
        const int ncol = n0 + wn * 64 + j * 16 + ccol;
        const float bv = bias[ncol];
#pragma unroll
        for (int r = 0; r < 4; ++r)
          ((float*)Cout)[(long)(mrow + r) * N + ncol] = acc[i][j][r] + bv;
      }
    }
  } else {
    // GLU same-lane + per-wave LDS transpose to pack stores as bf16x8.
    // Wave area: 16 rows x 32 ch, row stride 40 bf16 (pad for banks/alignment).
    __builtin_amdgcn_s_barrier();  // all waves done with K-loop LDS
    __bf16* wa = (__bf16*)Al + w * 640;
    const int chbase = (n0 >> 1) + wn * 32;
    const int rr = lane >> 2, c8 = (lane & 3) * 8;
#pragma unroll
    for (int i = 0; i < 8; ++i) {
#pragma unroll
      for (int j = 0; j < 2; ++j) {
        const int na = n0 + wn * 64 + j * 16 + ccol;
        const float bva = bias[na];
        const float bvg = bias[na + 32];
#pragma unroll
        for (int r = 0; r < 4; ++r) {
          float a = acc[i][j][r] + bva;
          float gv = acc[i][j + 2][r] + bvg;
          float res = a * __builtin_amdgcn_rcpf(1.f + __expf(-gv));
          wa[(crow + r) * 40 + j * 16 + ccol] = (__bf16)res;
        }
      }
      bf16x8 v = *(const bf16x8*)(wa + rr * 40 + c8);
      const int gr = m0 + wm * 128 + i * 16 + rr;
      *(bf16x8*)((__bf16*)Cout + (long)gr * (N >> 1) + chbase + c8) = v;
    }
  }
#undef TILE
#undef STAGEG
#undef PH_MID
#undef PH_END
#undef RDA
#undef RDB
#undef MMQ
#undef ADST
#undef BDST
#undef AWG
#undef BWG
}

__global__ __launch_bounds__(512, 2)
void gemm1_glu_kernel(const __bf16* __restrict__ A, const __bf16* __restrict__ Bw,
                      const float* __restrict__ bias, void* __restrict__ Cout,
                      int M, int N, int K, int ntn) {
  gemm_body<1>(A, Bw, bias, Cout, M, N, K, ntn);
}

__global__ __launch_bounds__(512, 2)
void gemm2_out_kernel(const __bf16* __restrict__ A, const __bf16* __restrict__ Bw,
                      const float* __restrict__ bias, void* __restrict__ Cout,
                      int M, int N, int K, int ntn) {
  gemm_body<0>(A, Bw, bias, Cout, M, N, K, ntn);
}

// ------- depthwise conv (K=31, pad 15) + bias + mask (input already GLU'd) ----
__global__ __launch_bounds__(256, 2)
void conv_kernel(const __bf16* __restrict__ Yin, const float* __restrict__ Wsm,
                 const float* __restrict__ bias, const int* __restrict__ mask,
                 __bf16* __restrict__ Y) {
  const int b  = blockIdx.z;
  const int t0 = blockIdx.y * 64;
  const int c0 = blockIdx.x * 128;
  __shared__ float sgT[128][128];
  __shared__ float swl[124];
  const int tid = threadIdx.x;
  if (tid < 124) swl[tid] = Wsm[tid];

  for (int i = tid; i < 2048; i += 256) {
    const int ttl = i & 127;  // tap 0..127 (94 used)
    const int cg  = i >> 7;   // channel octet 0..15
    if (ttl < 94) {
      const int t = t0 - 15 + ttl;
      float v[8];
      if (t >= 0 && t < 1024) {
        bf16x8 a8 = *(const bf16x8*)(Yin + ((long)(b * 1024 + t)) * 1024 + c0 + cg * 8);
#pragma unroll
        for (int j = 0; j < 8; ++j) v[j] = (float)a8[j];
      } else {
#pragma unroll
        for (int j = 0; j < 8; ++j) v[j] = 0.f;
      }
      const int q = ttl >> 2, e = ttl & 3;
#pragma unroll
      for (int j = 0; j < 8; ++j) {
        const int c = cg * 8 + j;
        sgT[c][((q ^ ((c & 7) << 2)) << 2) + e] = v[j];
      }
    }
  }
  __syncthreads();

  const int cc = tid & 127;
  const int th = tid >> 7;
  const int c  = c0 + cc;
  const float* wrow = swl + (c & 3) * 31;
  const float bv = bias[c];
  float acc[32];
#pragma unroll
  for (int u = 0; u < 32; ++u) acc[u] = bv;
  const int key = (cc & 7) << 2;
#pragma unroll
  for (int qi = 0; qi < 16; ++qi) {
    const int q = th * 8 + qi;
    const f32x4 w4 = *(const f32x4*)&sgT[cc][(q ^ key) << 2];
#pragma unroll
    for (int j = 0; j < 4; ++j) {
      const int rl = qi * 4 + j;
#pragma unroll
      for (int u = 0; u < 32; ++u) {
        const int k = rl - u;
        if (k >= 0 && k < 31) acc[u] += w4[j] * wrow[k];
      }
    }
  }
  const long yb = (long)b * 1024 * 1024;
#pragma unroll
  for (int u = 0; u < 32; ++u) {
    const int gt = t0 + th * 32 + u;
    float v = acc[u];
    if (mask[b * 1024 + gt] == 0) v = 0.f;
    Y[yb + (long)gt * 1024 + c] = (__bf16)v;
  }
}

extern "C" void kernel_launch(void* const* d_in, const int* in_sizes, int n_in,
                              void* d_out, int out_size, void* d_ws, size_t ws_size,
                              hipStream_t stream) {
  const float* q    = (const float*)d_in[0];
  const int*   mask = (const int*)d_in[3];
  const float* W1   = (const float*)d_in[4];
  const float* b1   = (const float*)d_in[5];
  const float* W2   = (const float*)d_in[6];
  const float* b2   = (const float*)d_in[7];
  const float* cw   = (const float*)d_in[8];
  const float* bias = (const float*)d_in[9];

  char* ws = (char*)d_ws;
  __bf16* q_bf  = (__bf16*)(ws);                // 32 MB; dead after GEMM1 -> reused as yc
  __bf16* w1p   = (__bf16*)(ws + (32u << 20));  // 4 MB (permuted)
  __bf16* w2_bf = (__bf16*)(ws + (36u << 20));  // 2 MB
  float*  swm   = (float*)(ws + (38u << 20));   // 496 B
  float*  b1p   = (float*)(ws + (38u << 20) + 4096);  // 8 KB (permuted)
  __bf16* y     = (__bf16*)d_out;               // (B,T,C) bf16 = 32 MB; dead after conv
  __bf16* yc    = q_bf;                         // conv output over dead q_bf

  cvt_bf16_kernel<<<2048, 256, 0, stream>>>(q, q_bf, 16 * 1024 * 1024 / 4);
  prep_all_kernel<<<1281, 256, 0, stream>>>(W1, W2, cw, b1, w1p, w2_bf, swm, b1p);

  // GEMM1 (+b1, GLU fused) -> y bf16 (B,T,C) in d_out. grid 64x8=512.
  gemm1_glu_kernel<<<512, 512, 0, stream>>>(q_bf, w1p, b1p, (void*)y,
                                            16384, 2048, 1024, 8);
  // depthwise conv + bias + mask: y -> yc
  conv_kernel<<<dim3(8, 16, 16), 256, 0, stream>>>(y, swm, bias, mask, yc);
  // GEMM2 + b2 -> d_out f32. grid 64x4=256.
  gemm2_out_kernel<<<256, 512, 0, stream>>>(yc, w2_bf, b2, d_out,
                                            16384, 1024, 1024, 4);
}

// Round 8
// 157.650 us; speedup vs baseline: 1.5392x; 1.0348x over previous
//
#include <hip/hip_runtime.h>

typedef __attribute__((ext_vector_type(8))) __bf16 bf16x8;
typedef __attribute__((ext_vector_type(4))) __bf16 bf16x4;
typedef __attribute__((ext_vector_type(4))) float  f32x4;
typedef __attribute__((ext_vector_type(4))) float  float4v;

#define DEV static __device__ __forceinline__

DEV void gload_lds16(const void* g, void* l) {
  __builtin_amdgcn_global_load_lds(
      (const __attribute__((address_space(1))) void*)g,
      (__attribute__((address_space(3))) void*)l, 16, 0, 0);
}

// ---- merged prep: q cvt | W1 perm-cvt | W2 cvt | softmax(conv_w)+b1 perm ----
// blocks 0..2047: q f32->bf16 (16M elems). 2048..3071: W1 same-lane GLU permute.
// 3072..3327: W2 cvt. 3328: softmax + b1p.
__global__ void prep_all_kernel(const float* __restrict__ q, const float* __restrict__ W1,
                                const float* __restrict__ W2, const float* __restrict__ cw,
                                const float* __restrict__ b1,
                                __bf16* __restrict__ qb, __bf16* __restrict__ w1p,
                                __bf16* __restrict__ w2b,
                                float* __restrict__ swm, float* __restrict__ b1p) {
  const int blk = blockIdx.x;
  const int tid = threadIdx.x;
  if (blk < 2048) {
    int i = blk * 256 + tid;
#pragma unroll 8
    for (int it = 0; it < 8; ++it, i += 524288) {
      float4v v = ((const float4v*)q)[i];
      bf16x4 o;
#pragma unroll
      for (int j = 0; j < 4; ++j) o[j] = (__bf16)v[j];
      ((bf16x4*)qb)[i] = o;
    }
  } else if (blk < 3072) {
    // out row n: g=n>>8, p=n&255, wn=p>>6, jj=(p>>4)&3, c16=p&15;
    // ch = g*128 + wn*32 + (jj&1)*16 + c16; src = ch + (jj>=2)*1024.
    const int r   = (blk - 2048) * 2 + (tid >> 7);
    const int col = (tid & 127) * 8;
    const int g  = r >> 8, p = r & 255;
    const int wn = p >> 6, jj = (p >> 4) & 3, c16 = p & 15;
    const int ch = g * 128 + wn * 32 + (jj & 1) * 16 + c16;
    const int src = ch + (jj >= 2 ? 1024 : 0);
    const float* ptr = W1 + (long)src * 1024 + col;
    float4v v0 = *(const float4v*)ptr;
    float4v v1 = *(const float4v*)(ptr + 4);
    bf16x8 o;
#pragma unroll
    for (int j = 0; j < 4; ++j) { o[j] = (__bf16)v0[j]; o[4 + j] = (__bf16)v1[j]; }
    *(bf16x8*)(w1p + (long)r * 1024 + col) = o;
  } else if (blk < 3328) {
    int i = (blk - 3072) * 256 + tid;  // 262144 float4s total
#pragma unroll 4
    for (int it = 0; it < 4; ++it, i += 65536) {
      float4v v = ((const float4v*)W2)[i];
      bf16x4 o;
#pragma unroll
      for (int j = 0; j < 4; ++j) o[j] = (__bf16)v[j];
      ((bf16x4*)w2b)[i] = o;
    }
  } else {
    if (tid < 4) {
      const int h = tid;
      float m = cw[h * 31];
#pragma unroll
      for (int k = 1; k < 31; ++k) m = fmaxf(m, cw[h * 31 + k]);
      float e[31];
      float s = 0.f;
#pragma unroll
      for (int k = 0; k < 31; ++k) {
        e[k] = __expf(cw[h * 31 + k] - m);
        s += e[k];
      }
      float inv = 1.f / s;
#pragma unroll
      for (int k = 0; k < 31; ++k) swm[h * 31 + k] = e[k] * inv;
    }
    for (int i = tid; i < 2048; i += 256) {
      const int g = i >> 8, p = i & 255;
      const int wn = p >> 6, jj = (p >> 4) & 3, c16 = p & 15;
      const int ch = g * 128 + wn * 32 + (jj & 1) * 16 + c16;
      b1p[i] = b1[ch + (jj >= 2 ? 1024 : 0)];
    }
  }
}

// ====== 256x256 GEMM, 4 phases/tile, 3-slot rotating A prefetch, no drain ======
// Granule [128 rows][64 k] bf16 = 16KB (full 128B lines). A: 3 slots x 32KB
// (2 granules), B: 2 slots x 32KB. LDS = 160KB exactly, 1 block/CU.
// Per tile t: ph0 {rdA03+rdB01; stage B(t+1)}  MFMA q00
//             ph1 {rdB23;       stage A(t+2)}  MFMA q01
//             ph2 {rdA47}                      MFMA q10
//             ph3 {}            vmcnt(4)       MFMA q11   <- only wait, never 0
// Slack: A ~7 phases, B ~3 phases. Slots rotated via runtime pointers.
template <int MODE>
DEV void gemm_body(const __bf16* __restrict__ A, const __bf16* __restrict__ Bw,
                   const float* __restrict__ bias, void* __restrict__ Cout,
                   int M, int N, int K, int ntn) {
  __shared__ __align__(16) __bf16 Al[3 * 16384];  // 96KB
  __shared__ __align__(16) __bf16 Bl[2 * 16384];  // 64KB

  const int tid  = threadIdx.x;
  const int lane = tid & 63;
  const int w    = tid >> 6;
  const int wm = w >> 2, wn = w & 3;

  const int nwg = gridDim.x;
  const int cpx = nwg >> 3;
  const int bid = blockIdx.x;
  const int wgid = (bid & 7) * cpx + (bid >> 3);
  const int m0 = (wgid / ntn) * 256;
  const int n0 = (wgid % ntn) * 256;

  const int NT = K >> 6;

  const int scolE = ((((tid & 7) * 16) ^ (((tid >> 3) & 7) << 4)) >> 1);
  const __bf16* __restrict__ Abase = A + (long)m0 * K;
  const __bf16* __restrict__ Bbase = Bw + (long)n0 * K;

  const int l15 = lane & 15;
  const int xk  = (l15 & 7) << 4;
  const int a0  = l15 * 128 + (((lane >> 4) * 16) ^ xk);
  const int a1  = l15 * 128 + ((((lane >> 4) * 16) + 64) ^ xk);
  const int bq  = (wn & 1) * 8192;
  const int b0  = bq + a0;
  const int b1r = bq + a1;

  f32x4 acc[8][4];
#pragma unroll
  for (int i = 0; i < 8; ++i)
#pragma unroll
    for (int j = 0; j < 4; ++j) {
      acc[i][j][0] = 0.f; acc[i][j][1] = 0.f;
      acc[i][j][2] = 0.f; acc[i][j][3] = 0.f;
    }
  bf16x8 af[8], bf[8];

#define STAGEG(base, groff, ktc, dst)                                             \
  {                                                                               \
    const __bf16* _s = (base) + (long)((groff) + (tid >> 3)) * K + (ktc) + scolE; \
    gload_lds16(_s, (dst) + tid * 8);                                             \
    gload_lds16(_s + (long)64 * K, (dst) + 4096 + tid * 8);                       \
  }

#define PH_MID()                                     \
  __builtin_amdgcn_s_barrier();                      \
  asm volatile("s_waitcnt lgkmcnt(0)" ::: "memory"); \
  __builtin_amdgcn_s_setprio(1);

#define PH_ENDN()                                    \
  __builtin_amdgcn_s_setprio(0);                     \
  __builtin_amdgcn_s_barrier();

#define PH_END4()                                    \
  __builtin_amdgcn_s_setprio(0);                     \
  asm volatile("s_waitcnt vmcnt(4)" ::: "memory");   \
  __builtin_amdgcn_s_barrier();

#define RDA(IB, G)                                                    \
  _Pragma("unroll") for (int i2 = 0; i2 < 4; ++i2) {                  \
    af[i2 * 2 + 0] = *(const bf16x8*)((G) + ((IB) + i2) * 2048 + a0); \
    af[i2 * 2 + 1] = *(const bf16x8*)((G) + ((IB) + i2) * 2048 + a1); \
  }
#define RDB(JB, G)                                                                \
  _Pragma("unroll") for (int j2 = 0; j2 < 2; ++j2) {                              \
    bf[(JB) * 2 + j2 * 2 + 0] = *(const bf16x8*)((G) + ((JB) + j2) * 2048 + b0);  \
    bf[(JB) * 2 + j2 * 2 + 1] = *(const bf16x8*)((G) + ((JB) + j2) * 2048 + b1r); \
  }

#define MMQ(IB, JB)                                                           \
  _Pragma("unroll") for (int i2 = 0; i2 < 4; ++i2)                            \
  _Pragma("unroll") for (int j2 = 0; j2 < 2; ++j2)                            \
  _Pragma("unroll") for (int kk = 0; kk < 2; ++kk)                            \
      acc[(IB) + i2][(JB) + j2] = __builtin_amdgcn_mfma_f32_16x16x32_bf16(    \
          af[i2 * 2 + kk], bf[(JB) * 2 + j2 * 2 + kk], acc[(IB) + i2][(JB) + j2], 0, 0, 0);

  // rotating slot pointers (elems)
  __bf16* aRd = Al;              // A(t)
  __bf16* aNx = Al + 16384;      // A(t+1)
  __bf16* aSt = Al + 32768;      // A(t+2) dest
  __bf16* bRd = Bl;              // B(t)
  __bf16* bSt = Bl + 16384;      // B(t+1) dest

  // prologue: A(0) [4 ops], B(0) [4], A(1) [4]; vmcnt(4) retires A(0),B(0)
  STAGEG(Abase, 0,   0, aRd);
  STAGEG(Abase, 128, 0, aRd + 8192);
  STAGEG(Bbase, 0,   0, bRd);
  STAGEG(Bbase, 128, 0, bRd + 8192);
  {
    const int k1 = (1 < NT ? 1 : NT - 1) * 64;
    STAGEG(Abase, 0,   k1, aNx);
    STAGEG(Abase, 128, k1, aNx + 8192);
  }
  asm volatile("s_waitcnt vmcnt(4)" ::: "memory");
  __builtin_amdgcn_s_barrier();

#pragma unroll 1
  for (int t = 0; t < NT; ++t) {
    const int kB = ((t + 1 < NT) ? t + 1 : NT - 1) * 64;
    const int kA = ((t + 2 < NT) ? t + 2 : NT - 1) * 64;
    const char* aG = (const char*)aRd + wm * 16384;
    const char* bG = (const char*)bRd + (wn >> 1) * 16384;
    // ph0
    RDA(0, aG); RDB(0, bG);
    STAGEG(Bbase, 0,   kB, bSt);
    STAGEG(Bbase, 128, kB, bSt + 8192);
    PH_MID(); MMQ(0, 0); PH_ENDN();
    // ph1
    RDB(2, bG);
    STAGEG(Abase, 0,   kA, aSt);
    STAGEG(Abase, 128, kA, aSt + 8192);
    PH_MID(); MMQ(0, 2); PH_ENDN();
    // ph2
    RDA(4, aG);
    PH_MID(); MMQ(4, 0); PH_ENDN();
    // ph3
    PH_MID(); MMQ(4, 2); PH_END4();
    // rotate slots
    __bf16* ta = aRd; aRd = aNx; aNx = aSt; aSt = ta;
    __bf16* tb = bRd; bRd = bSt; bSt = tb;
  }

  // drain pending staging before LDS reuse / exit
  asm volatile("s_waitcnt vmcnt(0)" ::: "memory");

  // ---- epilogue: C/D layout col=lane&15, row=(lane>>4)*4+reg ----
  const int crow = (lane >> 4) * 4;
  const int ccol = lane & 15;
  if (MODE == 0) {
#pragma unroll
    for (int i = 0; i < 8; ++i) {
      const int mrow = m0 + wm * 128 + i * 16 + crow;
#pragma unroll
      for (int j = 0; j < 4; ++j) {
        const int ncol = n0 + wn * 64 + j * 16 + ccol;
        const float bv = bias[ncol];
#pragma unroll
        for (int r = 0; r < 4; ++r)
          ((float*)Cout)[(long)(mrow + r) * N + ncol] = acc[i][j][r] + bv;
      }
    }
  } else {
    // GLU same-lane + per-wave LDS transpose to pack stores as bf16x8.
    __builtin_amdgcn_s_barrier();  // all waves past K-loop LDS reads
    __bf16* wa = (__bf16*)Al + w * 640;
    const int chbase = (n0 >> 1) + wn * 32;
    const int rr = lane >> 2, c8 = (lane & 3) * 8;
#pragma unroll
    for (int i = 0; i < 8; ++i) {
#pragma unroll
      for (int j = 0; j < 2; ++j) {
        const int na = n0 + wn * 64 + j * 16 + ccol;
        const float bva = bias[na];
        const float bvg = bias[na + 32];
#pragma unroll
        for (int r = 0; r < 4; ++r) {
          float a = acc[i][j][r] + bva;
          float gv = acc[i][j + 2][r] + bvg;
          float res = a * __builtin_amdgcn_rcpf(1.f + __expf(-gv));
          wa[(crow + r) * 40 + j * 16 + ccol] = (__bf16)res;
        }
      }
      bf16x8 v = *(const bf16x8*)(wa + rr * 40 + c8);
      const int gr = m0 + wm * 128 + i * 16 + rr;
      *(bf16x8*)((__bf16*)Cout + (long)gr * (N >> 1) + chbase + c8) = v;
    }
  }
#undef STAGEG
#undef PH_MID
#undef PH_ENDN
#undef PH_END4
#undef RDA
#undef RDB
#undef MMQ
}

__global__ __launch_bounds__(512, 1)
void gemm1_glu_kernel(const __bf16* __restrict__ A, const __bf16* __restrict__ Bw,
                      const float* __restrict__ bias, void* __restrict__ Cout,
                      int M, int N, int K, int ntn) {
  gemm_body<1>(A, Bw, bias, Cout, M, N, K, ntn);
}

__global__ __launch_bounds__(512, 1)
void gemm2_out_kernel(const __bf16* __restrict__ A, const __bf16* __restrict__ Bw,
                      const float* __restrict__ bias, void* __restrict__ Cout,
                      int M, int N, int K, int ntn) {
  gemm_body<0>(A, Bw, bias, Cout, M, N, K, ntn);
}

// ------- depthwise conv (K=31, pad 15) + bias + mask (input already GLU'd) ----
__global__ __launch_bounds__(256, 2)
void conv_kernel(const __bf16* __restrict__ Yin, const float* __restrict__ Wsm,
                 const float* __restrict__ bias, const int* __restrict__ mask,
                 __bf16* __restrict__ Y) {
  const int b  = blockIdx.z;
  const int t0 = blockIdx.y * 64;
  const int c0 = blockIdx.x * 128;
  __shared__ float sgT[128][128];
  __shared__ float swl[124];
  const int tid = threadIdx.x;
  if (tid < 124) swl[tid] = Wsm[tid];

  for (int i = tid; i < 2048; i += 256) {
    const int ttl = i & 127;  // tap 0..127 (94 used)
    const int cg  = i >> 7;   // channel octet 0..15
    if (ttl < 94) {
      const int t = t0 - 15 + ttl;
      float v[8];
      if (t >= 0 && t < 1024) {
        bf16x8 a8 = *(const bf16x8*)(Yin + ((long)(b * 1024 + t)) * 1024 + c0 + cg * 8);
#pragma unroll
        for (int j = 0; j < 8; ++j) v[j] = (float)a8[j];
      } else {
#pragma unroll
        for (int j = 0; j < 8; ++j) v[j] = 0.f;
      }
      const int q = ttl >> 2, e = ttl & 3;
#pragma unroll
      for (int j = 0; j < 8; ++j) {
        const int c = cg * 8 + j;
        sgT[c][((q ^ ((c & 7) << 2)) << 2) + e] = v[j];
      }
    }
  }
  __syncthreads();

  const int cc = tid & 127;
  const int th = tid >> 7;
  const int c  = c0 + cc;
  const float* wrow = swl + (c & 3) * 31;
  const float bv = bias[c];
  float acc[32];
#pragma unroll
  for (int u = 0; u < 32; ++u) acc[u] = bv;
  const int key = (cc & 7) << 2;
#pragma unroll
  for (int qi = 0; qi < 16; ++qi) {
    const int q = th * 8 + qi;
    const f32x4 w4 = *(const f32x4*)&sgT[cc][(q ^ key) << 2];
#pragma unroll
    for (int j = 0; j < 4; ++j) {
      const int rl = qi * 4 + j;
#pragma unroll
      for (int u = 0; u < 32; ++u) {
        const int k = rl - u;
        if (k >= 0 && k < 31) acc[u] += w4[j] * wrow[k];
      }
    }
  }
  const long yb = (long)b * 1024 * 1024;
#pragma unroll
  for (int u = 0; u < 32; ++u) {
    const int gt = t0 + th * 32 + u;
    float v = acc[u];
    if (mask[b * 1024 + gt] == 0) v = 0.f;
    Y[yb + (long)gt * 1024 + c] = (__bf16)v;
  }
}

extern "C" void kernel_launch(void* const* d_in, const int* in_sizes, int n_in,
                              void* d_out, int out_size, void* d_ws, size_t ws_size,
                              hipStream_t stream) {
  const float* q    = (const float*)d_in[0];
  const int*   mask = (const int*)d_in[3];
  const float* W1   = (const float*)d_in[4];
  const float* b1   = (const float*)d_in[5];
  const float* W2   = (const float*)d_in[6];
  const float* b2   = (const float*)d_in[7];
  const float* cw   = (const float*)d_in[8];
  const float* bias = (const float*)d_in[9];

  char* ws = (char*)d_ws;
  __bf16* q_bf  = (__bf16*)(ws);                // 32 MB; dead after GEMM1 -> reused as yc
  __bf16* w1p   = (__bf16*)(ws + (32u << 20));  // 4 MB (permuted)
  __bf16* w2_bf = (__bf16*)(ws + (36u << 20));  // 2 MB
  float*  swm   = (float*)(ws + (38u << 20));   // 496 B
  float*  b1p   = (float*)(ws + (38u << 20) + 4096);  // 8 KB (permuted)
  __bf16* y     = (__bf16*)d_out;               // (B,T,C) bf16 = 32 MB; dead after conv
  __bf16* yc    = q_bf;                         // conv output over dead q_bf

  prep_all_kernel<<<3329, 256, 0, stream>>>(q, W1, W2, cw, b1,
                                            q_bf, w1p, w2_bf, swm, b1p);

  // GEMM1 (+b1, GLU fused) -> y bf16 (B,T,C) in d_out. grid 64x8=512.
  gemm1_glu_kernel<<<512, 512, 0, stream>>>(q_bf, w1p, b1p, (void*)y,
                                            16384, 2048, 1024, 8);
  // depthwise conv + bias + mask: y -> yc
  conv_kernel<<<dim3(8, 16, 16), 256, 0, stream>>>(y, swm, bias, mask, yc);
  // GEMM2 + b2 -> d_out f32. grid 64x4=256.
  gemm2_out_kernel<<<256, 512, 0, stream>>>(yc, w2_bf, b2, d_out,
                                            16384, 1024, 1024, 4);
}